// Round 11
// baseline (305.365 us; speedup 1.0000x reference)
//
#include <hip/hip_runtime.h>
#include <stdint.h>
#include <stddef.h>

// ---------------------------------------------------------------------------
// SimpleRNN (gated linear attention) — chunked parallel formulation.
//   q = hs@Wq^T+bq ; k = sig(hs@Wk^T+bk) ; g = sig(hs@Wg^T+bg) ; v = hs@Wv^T+bv
//   S_t = diag(g_t) S_{t-1} + k_t v_t^T ; out_t = q_t S_t ; y = out@Wo^T+bo
// Chunked (C=64): la = within-chunk cumsum(log g) [fused in k_transform],
//   q~ = q*exp(la), k~ = k*exp(-la), kbar = k*exp(laC-la)
//   out = tril(q~ k~^T) V  +  q~ @ S_prev
//   U_c = kbar^T V ;  S_c = exp(laC) (.) S_{c-1} + U_c
//
// R11 = R9 block mappings (R10's XCD swizzle REGRESSED: projA FETCH 83->186MB
// because m0-fast order already keeps each XCD's hs slice L2-resident) +
// k_uscan S_c store coalescing via LDS restage (R10's other change, now
// isolated: 2x bf16x8 coalesced stores vs 16 scalar 2B scatters on the
// 128MB S-store stream).
// ---------------------------------------------------------------------------

#define DEVI __device__ __forceinline__

typedef __bf16 bf16;
typedef __bf16 bf16x8 __attribute__((ext_vector_type(8)));
typedef __bf16 bf16x4 __attribute__((ext_vector_type(4)));
typedef float  f32x4  __attribute__((ext_vector_type(4)));

static constexpr int T_  = 4096;
static constexpr int H_  = 2048;
static constexpr int KD  = 1024;
static constexpr int VD  = 1024;
static constexpr int OD  = 2048;
static constexpr int CH  = 64;                 // chunk length
static constexpr int NCHUNK = T_ / CH;         // 64
static constexpr int NGROUP = 2;               // chunk groups (ws economy)
static constexpr int CPG    = NCHUNK / NGROUP; // 32

DEVI bf16 tobf(float f) {
  union { float f; uint32_t u; } x; x.f = f;
  uint32_t r = (x.u + 0x7FFFu + ((x.u >> 16) & 1u)) >> 16;  // RNE
  union { uint16_t s; bf16 b; } y; y.s = (uint16_t)r;
  return y.b;
}

DEVI f32x4 fzero() { f32x4 z = {0.f, 0.f, 0.f, 0.f}; return z; }

// async global->LDS, 16B per lane (lane-linear LDS destination).
DEVI void gld16(const bf16* g, bf16* l) {
  auto* g1 = reinterpret_cast<__attribute__((address_space(1))) uint32_t*>(
      (uintptr_t)g);
  auto* l3 = reinterpret_cast<__attribute__((address_space(3))) uint32_t*>(
      (uintptr_t)l);
  __builtin_amdgcn_global_load_lds(g1, l3, 16, 0, 0);
}

template<int N> DEVI void waitvm() {
  if constexpr (N == 0) asm volatile("s_waitcnt vmcnt(0)" ::: "memory");
  else if constexpr (N == 2) asm volatile("s_waitcnt vmcnt(2)" ::: "memory");
  else if constexpr (N == 3) asm volatile("s_waitcnt vmcnt(3)" ::: "memory");
  else if constexpr (N == 4) asm volatile("s_waitcnt vmcnt(4)" ::: "memory");
  else static_assert(N == 0, "unsupported vmcnt");
}

// C[m0..+BM, n0..+BN] += A[M,K] * B[N,K]^T, both row-major K-contiguous.
// 4 waves in 2x2; BK=32; 3-buffer counted pipeline (R5/R7 — best measured).
template<int BM, int BN>
DEVI void gemm_core(const bf16* A, int lda, int m0,
                    const bf16* B, int ldb, int n0,
                    int K, f32x4* acc, bf16* sA, bf16* sB, int tid)
{
  constexpr int MR = BM / 32;
  constexpr int NR = BN / 32;
  constexpr int ASZ = BM * 32;
  constexpr int BSZ = BN * 32;
  constexpr int LOADS = BM / 64 + BN / 64;
  const int lane = tid & 63;
  const int wr = (tid >> 6) >> 1;
  const int wc = (tid >> 6) & 1;
  const int srow = tid >> 2;
  const int skof = (tid & 3) * 8;
  const bf16* aB = A + (size_t)(m0 + srow) * lda + skof;
  const bf16* bB = B + (size_t)(n0 + srow) * ldb + skof;

  auto stage = [&](int t, int buf) {
    const int k0 = t * 32;
#pragma unroll
    for (int r = 0; r < BM / 64; ++r)
      gld16(aB + (size_t)r * 64 * lda + k0, sA + buf * ASZ + r * 2048 + tid * 8);
#pragma unroll
    for (int r = 0; r < BN / 64; ++r)
      gld16(bB + (size_t)r * 64 * ldb + k0, sB + buf * BSZ + r * 2048 + tid * 8);
  };

  const int nt = K / 32;
  stage(0, 0);
  if (nt > 1) stage(1, 1);
  int cur = 0;
  for (int t = 0; t < nt; ++t) {
    if (t < nt - 1) waitvm<LOADS>();
    else            waitvm<0>();
    __builtin_amdgcn_s_barrier();
    __builtin_amdgcn_sched_barrier(0);
    if (t + 2 < nt) {
      int b2 = cur + 2; if (b2 >= 3) b2 -= 3;
      stage(t + 2, b2);
    }
    const bf16* pA = sA + cur * ASZ;
    const bf16* pB = sB + cur * BSZ;
    bf16x8 af[MR], bfr[NR];
#pragma unroll
    for (int m = 0; m < MR; ++m)
      af[m] = *(const bf16x8*)(pA + (wr * (MR * 16) + m * 16 + (lane & 15)) * 32
                               + (lane >> 4) * 8);
#pragma unroll
    for (int n = 0; n < NR; ++n)
      bfr[n] = *(const bf16x8*)(pB + (wc * (NR * 16) + n * 16 + (lane & 15)) * 32
                                + (lane >> 4) * 8);
#pragma unroll
    for (int m = 0; m < MR; ++m)
#pragma unroll
      for (int n = 0; n < NR; ++n)
        acc[m * NR + n] = __builtin_amdgcn_mfma_f32_16x16x32_bf16(
            af[m], bfr[n], acc[m * NR + n], 0, 0, 0);
    ++cur; if (cur >= 3) cur -= 3;
  }
}

// ---------------------------------------------------------------------------
static constexpr size_t CVT_HS = (size_t)T_ * H_;
static constexpr size_t CVT_W  = (size_t)KD * H_;
static constexpr size_t CVT_WO = (size_t)OD * VD;
static constexpr size_t CVT_TOT = CVT_HS + 4 * CVT_W + CVT_WO;

__global__ __launch_bounds__(256) void k_cvt6(
    const float* __restrict__ hs, const float* __restrict__ Wq,
    const float* __restrict__ Wk, const float* __restrict__ Wg,
    const float* __restrict__ Wv, const float* __restrict__ Wo,
    bf16* __restrict__ hsb, bf16* __restrict__ Wqb,
    bf16* __restrict__ Wkb, bf16* __restrict__ Wgb,
    bf16* __restrict__ Wvb, bf16* __restrict__ Wob)
{
  size_t i = ((size_t)blockIdx.x * 256 + threadIdx.x) * 4;
  if (i >= CVT_TOT) return;
  const float* s; bf16* d; size_t off;
  if (i < CVT_HS)                { s = hs; d = hsb; off = i; }
  else if (i < CVT_HS + CVT_W)   { s = Wq; d = Wqb; off = i - CVT_HS; }
  else if (i < CVT_HS + 2*CVT_W) { s = Wk; d = Wkb; off = i - CVT_HS - CVT_W; }
  else if (i < CVT_HS + 3*CVT_W) { s = Wg; d = Wgb; off = i - CVT_HS - 2*CVT_W; }
  else if (i < CVT_HS + 4*CVT_W) { s = Wv; d = Wvb; off = i - CVT_HS - 3*CVT_W; }
  else                           { s = Wo; d = Wob; off = i - CVT_HS - 4*CVT_W; }
  float4 v = *(const float4*)(s + off);
  bf16x4 o; o[0] = tobf(v.x); o[1] = tobf(v.y); o[2] = tobf(v.z); o[3] = tobf(v.w);
  *(bf16x4*)(d + off) = o;
}

// K-split projection GEMM: grid (32 m, 32 nseg, 2 kh); bf16 partials.
// m0-fast dispatch order keeps each XCD's hs slice L2-resident (R10 lesson:
// do NOT swizzle this grid).
__global__ __launch_bounds__(256) void k_projA(
    const bf16* __restrict__ hsb,
    const bf16* __restrict__ Wqb, const bf16* __restrict__ Wkb,
    const bf16* __restrict__ Wgb, const bf16* __restrict__ Wvb,
    bf16* __restrict__ pbuf)
{
  __shared__ __align__(16) bf16 sA[3 * 128 * 32];
  __shared__ __align__(16) bf16 sB[3 * 128 * 32];
  const int m0 = blockIdx.x * 128;
  const int nseg = blockIdx.y;          // 0..31
  const int kh = blockIdx.z;            // 0..1
  const int seg = nseg >> 3;
  const int n0 = (nseg & 7) * 128;
  const bf16* W = seg == 0 ? Wqb : seg == 1 ? Wkb : seg == 2 ? Wgb : Wvb;
  const int tid = threadIdx.x, lane = tid & 63;
  const int wr = (tid >> 6) >> 1, wc = (tid >> 6) & 1;
  f32x4 acc[16];
#pragma unroll
  for (int i = 0; i < 16; ++i) acc[i] = fzero();
  gemm_core<128, 128>(hsb + kh * 1024, H_, m0, W + kh * 1024, H_, n0, 1024,
                      acc, sA, sB, tid);
  bf16* dst = pbuf + (size_t)kh * T_ * 4096;
#pragma unroll
  for (int m = 0; m < 4; ++m)
#pragma unroll
    for (int n = 0; n < 4; ++n) {
      f32x4 v = acc[m * 4 + n];
      int colF = seg * 1024 + n0 + wc * 64 + n * 16 + (lane & 15);
#pragma unroll
      for (int r = 0; r < 4; ++r) {
        int row = m0 + wr * 64 + m * 16 + (lane >> 4) * 4 + r;
        dst[(size_t)row * 4096 + colF] = tobf(v[r]);
      }
    }
}

// reduce partials + bias + activations -> qb / kb / la / vb
__global__ __launch_bounds__(256) void k_projB(
    const bf16* __restrict__ pbuf,
    const float* __restrict__ bq, const float* __restrict__ bk,
    const float* __restrict__ bg, const float* __restrict__ bv,
    bf16* __restrict__ qb, bf16* __restrict__ kb,
    float* __restrict__ la, bf16* __restrict__ vb)
{
  size_t i = ((size_t)blockIdx.x * 256 + threadIdx.x) * 8;   // over T_*4096
  int row = (int)(i >> 12), colF = (int)(i & 4095);
  int seg = colF >> 10, col = colF & 1023;
  bf16x8 p0 = *(const bf16x8*)(pbuf + i);
  bf16x8 p1 = *(const bf16x8*)(pbuf + (size_t)T_ * 4096 + i);
  const float* bias = seg == 0 ? bq : seg == 1 ? bk : seg == 2 ? bg : bv;
  float4 b0 = *(const float4*)(bias + col);
  float4 b1 = *(const float4*)(bias + col + 4);
  float x[8];
#pragma unroll
  for (int j = 0; j < 8; ++j) {
    float b = j < 4 ? (&b0.x)[j] : (&b1.x)[j - 4];
    x[j] = (float)p0[j] + (float)p1[j] + b;
  }
  size_t o = (size_t)row * KD + col;
  if (seg == 2) {
    float4 o0, o1;
#pragma unroll
    for (int j = 0; j < 4; ++j)
      (&o0.x)[j] = fminf(x[j], 0.f) - log1pf(expf(-fabsf(x[j])));
#pragma unroll
    for (int j = 0; j < 4; ++j)
      (&o1.x)[j] = fminf(x[4 + j], 0.f) - log1pf(expf(-fabsf(x[4 + j])));
    *(float4*)(la + o) = o0; *(float4*)(la + o + 4) = o1;
  } else {
    bf16x8 ov;
#pragma unroll
    for (int j = 0; j < 8; ++j) {
      float y = (seg == 1) ? 1.f / (1.f + expf(-x[j])) : x[j];
      ov[j] = tobf(y);
    }
    bf16* dst = seg == 0 ? qb : seg == 1 ? kb : vb;
    *(bf16x8*)(dst + o) = ov;
  }
}

// path0: fused within-chunk prefix of log g + decay-weighted operands.
// path1: V^T [c][vv][t].
__global__ __launch_bounds__(256) void k_transform(
    const bf16* __restrict__ qb, const bf16* __restrict__ kb,
    const float* __restrict__ la, const bf16* __restrict__ vb,
    bf16* __restrict__ qt, bf16* __restrict__ kt,
    bf16* __restrict__ kbarT, bf16* __restrict__ vT,
    float* __restrict__ laC)
{
  __shared__ bf16 tr[64][72];
  __shared__ float gtot[4][64];
  const int c = blockIdx.y, tile = blockIdx.x, path = blockIdx.z;
  const int tid = threadIdx.x;
  const int colL = tid & 63;
  const int grp = tid >> 6;            // 0..3
  if (path == 0) {
    const int kk0 = tile * 64;
    const int kk = kk0 + colL;
    float lraw[16];
    float run = 0.f;
#pragma unroll
    for (int i = 0; i < 16; ++i) {
      int t = grp * 16 + i;
      lraw[i] = la[(size_t)(c * CH + t) * KD + kk];
      run += lraw[i];
    }
    gtot[grp][colL] = run;
    __syncthreads();
    float off = 0.f, lc = 0.f;
#pragma unroll
    for (int g2 = 0; g2 < 4; ++g2) {
      float v = gtot[g2][colL];
      if (g2 < grp) off += v;
      lc += v;
    }
    if (grp == 0) laC[(size_t)c * KD + kk] = lc;
    float run2 = off;
#pragma unroll
    for (int i = 0; i < 16; ++i) {
      int t = grp * 16 + i;
      run2 += lraw[i];
      size_t idx = (size_t)(c * CH + t) * KD + kk;
      float qv = (float)qb[idx];
      float kv = (float)kb[idx];
      qt[idx] = tobf(qv * expf(run2));
      kt[idx] = tobf(kv * expf(-run2));
      tr[colL][t] = tobf(kv * expf(lc - run2));   // kbar, staged for transpose
    }
    __syncthreads();
#pragma unroll
    for (int i = 0; i < 16; ++i) {
      int row = grp + 4 * i;
      kbarT[((size_t)c * KD + kk0 + row) * 64 + colL] = tr[row][colL];
    }
  } else {
    const int vv0 = tile * 64;
#pragma unroll
    for (int i = 0; i < 16; ++i) {
      int t = grp + 4 * i;
      tr[colL][t] = vb[(size_t)(c * CH + t) * VD + vv0 + colL];
    }
    __syncthreads();
#pragma unroll
    for (int i = 0; i < 16; ++i) {
      int row = grp + 4 * i;
      vT[((size_t)c * VD + vv0 + row) * 64 + colL] = tr[row][colL];
    }
  }
}

// K-split QK^T partials: Ppart[c][ks] = q~ slice @ k~ slice^T (fp32)
__global__ __launch_bounds__(256) void k_qkt(
    const bf16* __restrict__ qt, const bf16* __restrict__ kt,
    float* __restrict__ Ppart)
{
  __shared__ __align__(16) bf16 sA[3 * 64 * 32];
  __shared__ __align__(16) bf16 sB[3 * 64 * 32];
  const int ks = blockIdx.x, c = blockIdx.y;
  const int tid = threadIdx.x, lane = tid & 63;
  const int wr = (tid >> 6) >> 1, wc = (tid >> 6) & 1;
  f32x4 acc[4];
#pragma unroll
  for (int i = 0; i < 4; ++i) acc[i] = fzero();
  gemm_core<64, 64>(qt + (size_t)c * CH * KD + ks * 256, KD, 0,
                    kt + (size_t)c * CH * KD + ks * 256, KD, 0, 256,
                    acc, sA, sB, tid);
  float* dst = Ppart + ((size_t)c * 4 + ks) * 4096;
#pragma unroll
  for (int m = 0; m < 2; ++m)
#pragma unroll
    for (int n = 0; n < 2; ++n) {
      f32x4 v = acc[m * 2 + n];
      int j = wc * 32 + n * 16 + (lane & 15);
#pragma unroll
      for (int r = 0; r < 4; ++r) {
        int t = wr * 32 + m * 16 + (lane >> 4) * 4 + r;
        dst[t * 64 + j] = v[r];
      }
    }
}

// fused U-GEMM + decay scan (S in MFMA accumulator, fp32 across chunks).
// S_c stores coalesced via LDS restage (R10 change, isolated here).
__global__ __launch_bounds__(256) void k_uscan(
    const bf16* __restrict__ vT, const bf16* __restrict__ kbarT,
    const float* __restrict__ laC, bf16* __restrict__ Sstore,
    float* __restrict__ Sinit, bf16* __restrict__ ScarryB,
    float* __restrict__ dstate, int g)
{
  __shared__ __align__(16) bf16 sA[3 * 4096];   // [buf][ks*2048 + row*32 + kof]
  __shared__ __align__(16) bf16 sB[3 * 4096];
  __shared__ __align__(16) bf16 sS[64 * 72];    // coalescing restage
  const int vv0 = blockIdx.x * 64, kk0 = blockIdx.y * 64;
  const int tid = threadIdx.x, lane = tid & 63;
  const int wr = (tid >> 6) >> 1, wc = (tid >> 6) & 1;
  const int srow = tid >> 2, skof = (tid & 3) * 8;

  auto stage = [&](int cl, int buf) {
    const int c = g * CPG + cl;
    const bf16* vP = vT + ((size_t)c * VD + vv0 + srow) * 64 + skof;
    const bf16* kP = kbarT + ((size_t)c * KD + kk0 + srow) * 64 + skof;
    gld16(vP,      sA + buf * 4096 + tid * 8);
    gld16(vP + 32, sA + buf * 4096 + 2048 + tid * 8);
    gld16(kP,      sB + buf * 4096 + tid * 8);
    gld16(kP + 32, sB + buf * 4096 + 2048 + tid * 8);
  };

  // S fragment coordinates (C/D layout): col = col0 + n*16, row = row0 + m*16 + r
  const int col0 = kk0 + wc * 32 + (lane & 15);
  const int row0 = vv0 + wr * 32 + (lane >> 4) * 4;

  f32x4 S[4];
  if (g == 0) {
#pragma unroll
    for (int i = 0; i < 4; ++i) S[i] = fzero();
  } else {
#pragma unroll
    for (int m = 0; m < 2; ++m)
#pragma unroll
      for (int n = 0; n < 2; ++n)
#pragma unroll
        for (int r = 0; r < 4; ++r)
          S[m * 2 + n][r] =
              Sinit[(size_t)(row0 + m * 16 + r) * KD + col0 + n * 16];
  }

  stage(0, 0);
  stage(1, 1);
  float ln0 = laC[(size_t)(g * CPG) * KD + col0];
  float ln1 = laC[(size_t)(g * CPG) * KD + col0 + 16];

  for (int cl = 0; cl < CPG; ++cl) {
    if (cl < CPG - 1) waitvm<4>();
    else              waitvm<0>();
    __builtin_amdgcn_s_barrier();
    __builtin_amdgcn_sched_barrier(0);
    const float d0 = expf(ln0), d1 = expf(ln1);
#pragma unroll
    for (int m = 0; m < 2; ++m)
#pragma unroll
      for (int r = 0; r < 4; ++r) {
        S[m * 2 + 0][r] *= d0;
        S[m * 2 + 1][r] *= d1;
      }
    int buf = cl % 3;
    const bf16* pA = sA + buf * 4096;
    const bf16* pB = sB + buf * 4096;
#pragma unroll
    for (int ks = 0; ks < 2; ++ks) {
      bf16x8 af[2], bfr[2];
#pragma unroll
      for (int m = 0; m < 2; ++m)
        af[m] = *(const bf16x8*)(pA + ks * 2048
                 + (wr * 32 + m * 16 + (lane & 15)) * 32 + (lane >> 4) * 8);
#pragma unroll
      for (int n = 0; n < 2; ++n)
        bfr[n] = *(const bf16x8*)(pB + ks * 2048
                 + (wc * 32 + n * 16 + (lane & 15)) * 32 + (lane >> 4) * 8);
#pragma unroll
      for (int m = 0; m < 2; ++m)
#pragma unroll
        for (int n = 0; n < 2; ++n)
          S[m * 2 + n] = __builtin_amdgcn_mfma_f32_16x16x32_bf16(
              af[m], bfr[n], S[m * 2 + n], 0, 0, 0);
    }
    // restage S_c through LDS -> coalesced bf16x8 stores (128B per 4 lanes).
    // Hazard: next chunk's sS writes occur after the top-of-loop barrier,
    // which all waves reach only after finishing their sS reads here.
#pragma unroll
    for (int m = 0; m < 2; ++m)
#pragma unroll
      for (int n = 0; n < 2; ++n)
#pragma unroll
        for (int r = 0; r < 4; ++r)
          sS[(wr * 32 + m * 16 + (lane >> 4) * 4 + r) * 72
             + wc * 32 + n * 16 + (lane & 15)] = tobf(S[m * 2 + n][r]);
    asm volatile("s_waitcnt lgkmcnt(0)" ::: "memory");
    __builtin_amdgcn_sched_barrier(0);
    __builtin_amdgcn_s_barrier();
    __builtin_amdgcn_sched_barrier(0);
    {
      bf16* dst = Sstore + (size_t)cl * KD * VD;
      const int row = tid >> 2, colb = (tid & 3) * 16;
      bf16x8 a = *(const bf16x8*)(sS + row * 72 + colb);
      bf16x8 b = *(const bf16x8*)(sS + row * 72 + colb + 8);
      *(bf16x8*)(dst + (size_t)(vv0 + row) * KD + kk0 + colb) = a;
      *(bf16x8*)(dst + (size_t)(vv0 + row) * KD + kk0 + colb + 8) = b;
    }
    if (cl + 1 < CPG) {
      ln0 = laC[(size_t)(g * CPG + cl + 1) * KD + col0];
      ln1 = laC[(size_t)(g * CPG + cl + 1) * KD + col0 + 16];
    }
    if (cl + 2 < CPG) stage(cl + 2, (cl + 2) % 3);
  }

  if (g < NGROUP - 1) {
    // carry: fp32 (scan continuation) + bf16 (inter2 B-operand)
#pragma unroll
    for (int m = 0; m < 2; ++m)
#pragma unroll
      for (int n = 0; n < 2; ++n)
#pragma unroll
        for (int r = 0; r < 4; ++r) {
          size_t o = (size_t)(row0 + m * 16 + r) * KD + col0 + n * 16;
          Sinit[o] = S[m * 2 + n][r];
          ScarryB[o] = tobf(S[m * 2 + n][r]);
        }
  } else {
    // final state -> dstate [kk][vv] via LDS transpose (reuse sA as fp32)
    float* flds = (float*)sA;                // 64x65 fp32 = 16.6KB < 24KB
    __syncthreads();
#pragma unroll
    for (int m = 0; m < 2; ++m)
#pragma unroll
      for (int n = 0; n < 2; ++n)
#pragma unroll
        for (int r = 0; r < 4; ++r)
          flds[(wr * 32 + m * 16 + (lane >> 4) * 4 + r) * 65
               + wc * 32 + n * 16 + (lane & 15)] = S[m * 2 + n][r];
    __syncthreads();
    const int kkL = tid & 63;
    const int vb0 = (tid >> 6) * 16;
    float* dp = dstate + (size_t)(kk0 + kkL) * VD + vv0 + vb0;
#pragma unroll
    for (int q = 0; q < 4; ++q) {
      float4 o = {flds[(vb0 + q * 4 + 0) * 65 + kkL],
                  flds[(vb0 + q * 4 + 1) * 65 + kkL],
                  flds[(vb0 + q * 4 + 2) * 65 + kkL],
                  flds[(vb0 + q * 4 + 3) * 65 + kkL]};
      *(float4*)(dp + q * 4) = o;
    }
  }
}

// fused: P assemble + inter GEMM (q~_c @ S_{c-1}) + PV (128-col slice)
// -> ob = bf16(intra + inter). grid (8 ntiles, CPG chunks).
__global__ __launch_bounds__(256) void k_inter2(
    const bf16* __restrict__ qt, const float* __restrict__ Ppart,
    const bf16* __restrict__ vT, const bf16* __restrict__ Sstore,
    const bf16* __restrict__ ScarryB, bf16* __restrict__ ob, int g)
{
  __shared__ __align__(16) bf16 sA[3 * 64 * 32];
  __shared__ __align__(16) bf16 sB[3 * 128 * 32];
  __shared__ __align__(16) bf16 Pl[64 * 72];
  __shared__ __align__(16) bf16 sV[128 * 72];
  const int cl = blockIdx.y, c = g * CPG + cl;
  const int n0 = blockIdx.x * 128;
  const int tid = threadIdx.x, lane = tid & 63;
  const int wr = (tid >> 6) >> 1, wc = (tid >> 6) & 1;

  // assemble P = sum of 4 K-partials, causal mask, bf16 into Pl
  {
    const float* base = Ppart + (size_t)c * 4 * 4096;
    const int i0 = tid * 16;
    const int t = tid >> 2;
    const int j0 = (tid & 3) * 16;
#pragma unroll
    for (int e = 0; e < 16; e += 4) {
      float4 s0 = *(const float4*)(base + 0 * 4096 + i0 + e);
      float4 s1 = *(const float4*)(base + 1 * 4096 + i0 + e);
      float4 s2 = *(const float4*)(base + 2 * 4096 + i0 + e);
      float4 s3 = *(const float4*)(base + 3 * 4096 + i0 + e);
      float sx = s0.x + s1.x + s2.x + s3.x;
      float sy = s0.y + s1.y + s2.y + s3.y;
      float sz = s0.z + s1.z + s2.z + s3.z;
      float sw = s0.w + s1.w + s2.w + s3.w;
      int j = j0 + e;
      Pl[t * 72 + j + 0] = (j + 0 <= t) ? tobf(sx) : tobf(0.f);
      Pl[t * 72 + j + 1] = (j + 1 <= t) ? tobf(sy) : tobf(0.f);
      Pl[t * 72 + j + 2] = (j + 2 <= t) ? tobf(sz) : tobf(0.f);
      Pl[t * 72 + j + 3] = (j + 3 <= t) ? tobf(sw) : tobf(0.f);
    }
  }
  __syncthreads();

  f32x4 acc[8];
#pragma unroll
  for (int i = 0; i < 8; ++i) acc[i] = fzero();
  if (c > 0) {
    const bf16* B = (cl == 0) ? ScarryB : Sstore + (size_t)(cl - 1) * KD * VD;
    gemm_core<64, 128>(qt + (size_t)c * CH * KD, KD, 0, B, KD, n0, KD,
                       acc, sA, sB, tid);
  }

  // stage V^T slice rows [n0, n0+128) and add PV into acc
#pragma unroll
  for (int rr = 0; rr < 4; ++rr) {
    int row = rr * 32 + (tid >> 3);
    int j0 = (tid & 7) * 8;
    bf16x8 vv = *(const bf16x8*)(vT + ((size_t)c * VD + n0 + row) * 64 + j0);
    *(bf16x8*)(sV + row * 72 + j0) = vv;
  }
  __syncthreads();
#pragma unroll
  for (int ks = 0; ks < 64; ks += 32) {
    bf16x8 af[2], bfr[4];
#pragma unroll
    for (int m = 0; m < 2; ++m)
      af[m] = *(const bf16x8*)(Pl + (wr * 32 + m * 16 + (lane & 15)) * 72
                               + ks + (lane >> 4) * 8);
#pragma unroll
    for (int n = 0; n < 4; ++n)
      bfr[n] = *(const bf16x8*)(sV + (wc * 64 + n * 16 + (lane & 15)) * 72
                                + ks + (lane >> 4) * 8);
#pragma unroll
    for (int m = 0; m < 2; ++m)
#pragma unroll
      for (int n = 0; n < 4; ++n)
        acc[m * 4 + n] = __builtin_amdgcn_mfma_f32_16x16x32_bf16(
            af[m], bfr[n], acc[m * 4 + n], 0, 0, 0);
  }

#pragma unroll
  for (int m = 0; m < 2; ++m)
#pragma unroll
    for (int n = 0; n < 4; ++n) {
      f32x4 v = acc[m * 4 + n];
      int col = wc * 64 + n * 16 + (lane & 15);
#pragma unroll
      for (int r = 0; r < 4; ++r) {
        int row = wr * 32 + m * 16 + (lane >> 4) * 4 + r;
        ob[((size_t)c * CH + row) * VD + n0 + col] = tobf(v[r]);
      }
    }
}

// y = ob @ Wo^T + bo. BN=64: grid (32, 32) = 1024 blocks, 4/CU.
__global__ __launch_bounds__(256) void k_out(
    const bf16* __restrict__ ob, const bf16* __restrict__ Wob,
    const float* __restrict__ bo, float* __restrict__ out)
{
  __shared__ __align__(16) bf16 sA[3 * 128 * 32];
  __shared__ __align__(16) bf16 sB[3 * 64 * 32];
  const int m0 = blockIdx.x * 128, n0 = blockIdx.y * 64;
  const int tid = threadIdx.x, lane = tid & 63;
  const int wr = (tid >> 6) >> 1, wc = (tid >> 6) & 1;
  f32x4 acc[8];
#pragma unroll
  for (int i = 0; i < 8; ++i) acc[i] = fzero();
  gemm_core<128, 64>(ob, VD, m0, Wob, VD, n0, VD, acc, sA, sB, tid);
#pragma unroll
  for (int m = 0; m < 4; ++m)
#pragma unroll
    for (int n = 0; n < 2; ++n) {
      f32x4 v = acc[m * 2 + n];
      int col = n0 + wc * 32 + n * 16 + (lane & 15);
      float b = bo[col];
#pragma unroll
      for (int r = 0; r < 4; ++r) {
        int row = m0 + wr * 64 + m * 16 + (lane >> 4) * 4 + r;
        out[(size_t)row * OD + col] = v[r] + b;
      }
    }
}

// ---------------------------------------------------------------------------
extern "C" void kernel_launch(void* const* d_in, const int* in_sizes, int n_in,
                              void* d_out, int out_size, void* d_ws, size_t ws_size,
                              hipStream_t stream)
{
  const float* hs = (const float*)d_in[0];
  const float* Wq = (const float*)d_in[1];
  const float* bq = (const float*)d_in[2];
  const float* Wk = (const float*)d_in[3];
  const float* bk = (const float*)d_in[4];
  const float* Wv = (const float*)d_in[5];
  const float* bv = (const float*)d_in[6];
  const float* Wg = (const float*)d_in[7];
  const float* bg = (const float*)d_in[8];
  const float* Wo = (const float*)d_in[9];
  const float* bo = (const float*)d_in[10];
  float* out = (float*)d_out;
  float* dstate = out + (size_t)T_ * OD;

  char* p = (char*)d_ws;
  auto alloc = [&](size_t b) -> char* {
    char* r = p; p += (b + 255) & ~(size_t)255; return r;
  };
  bf16* hsb    = (bf16*)alloc((size_t)T_ * H_ * 2);
  bf16* Wqb    = (bf16*)alloc((size_t)KD * H_ * 2);
  bf16* Wkb    = (bf16*)alloc((size_t)KD * H_ * 2);
  bf16* Wgb    = (bf16*)alloc((size_t)KD * H_ * 2);
  bf16* Wvb    = (bf16*)alloc((size_t)VD * H_ * 2);
  bf16* Wob    = (bf16*)alloc((size_t)OD * VD * 2);
  bf16* qb     = (bf16*)alloc((size_t)T_ * KD * 2);
  bf16* kb     = (bf16*)alloc((size_t)T_ * KD * 2);
  float* la    = (float*)alloc((size_t)T_ * KD * 4);
  bf16* vb     = (bf16*)alloc((size_t)T_ * VD * 2);
  bf16* qt     = (bf16*)alloc((size_t)T_ * KD * 2);
  bf16* kt     = (bf16*)alloc((size_t)T_ * KD * 2);
  bf16* kbarT  = (bf16*)alloc((size_t)T_ * KD * 2);
  bf16* vT     = (bf16*)alloc((size_t)T_ * VD * 2);
  bf16* ob     = (bf16*)alloc((size_t)T_ * VD * 2);
  float* Sinit = (float*)alloc((size_t)KD * VD * 4);
  bf16* ScarryB= (bf16*)alloc((size_t)KD * VD * 2);
  bf16* Sstore = (bf16*)alloc((size_t)CPG * KD * VD * 2);   // 64 MB
  float* laC   = (float*)alloc((size_t)NCHUNK * KD * 4);
  float* Ppart = (float*)alloc((size_t)NCHUNK * 4 * 4096 * 4);
  if ((size_t)(p - (char*)d_ws) > ws_size) return;

  // pbuf (proj partials, 64MB bf16) reuses Sstore: free until first k_uscan.
  bf16* pbuf = Sstore;

  k_cvt6<<<(int)((CVT_TOT / 4 + 255) / 256), 256, 0, stream>>>(
      hs, Wq, Wk, Wg, Wv, Wo, hsb, Wqb, Wkb, Wgb, Wvb, Wob);

  k_projA<<<dim3(T_ / 128, 32, 2), 256, 0, stream>>>(
      hsb, Wqb, Wkb, Wgb, Wvb, pbuf);
  k_projB<<<(int)((size_t)T_ * 4096 / 8 / 256), 256, 0, stream>>>(
      pbuf, bq, bk, bg, bv, qb, kb, la, vb);

  k_transform<<<dim3(16, NCHUNK, 2), 256, 0, stream>>>(
      qb, kb, la, vb, qt, kt, kbarT, vT, laC);

  k_qkt<<<dim3(4, NCHUNK), 256, 0, stream>>>(qt, kt, Ppart);

  for (int g = 0; g < NGROUP; ++g) {
    k_uscan<<<dim3(16, 16), 256, 0, stream>>>(
        vT, kbarT, laC, Sstore, Sinit, ScarryB, dstate, g);
    k_inter2<<<dim3(8, CPG), 256, 0, stream>>>(
        qt, Ppart, vT, Sstore, ScarryB, ob, g);
  }

  k_out<<<dim3(T_ / 128, OD / 64), 256, 0, stream>>>(ob, Wob, bo, out);
}

// Round 12
// 287.208 us; speedup vs baseline: 1.0632x; 1.0632x over previous
//
#include <hip/hip_runtime.h>
#include <stdint.h>
#include <stddef.h>

// ---------------------------------------------------------------------------
// SimpleRNN (gated linear attention) — chunked parallel formulation.
//   q = hs@Wq^T+bq ; k = sig(hs@Wk^T+bk) ; g = sig(hs@Wg^T+bg) ; v = hs@Wv^T+bv
//   S_t = diag(g_t) S_{t-1} + k_t v_t^T ; out_t = q_t S_t ; y = out@Wo^T+bo
// Chunked (C=64): la = within-chunk cumsum(log g) [fused in k_transform],
//   q~ = q*exp(la), k~ = k*exp(-la), kbar = k*exp(laC-la)
//   out = tril(q~ k~^T) V  +  q~ @ S_prev
//   U_c = kbar^T V ;  S_c = exp(laC) (.) S_{c-1} + U_c
//
// R12 = R9 exactly (best measured: 291.5us; R10 swizzle and R11 store-restage
// both regressed and are reverted) + union kernel co-scheduling k_qkt with
// k_uscan(g=0): independent data, both 1-block/CU; merged grid (16,16,2)
// puts both co-resident (2 blocks/CU) so qkt's compute hides uscan's
// serial-chain latency.
// ---------------------------------------------------------------------------

#define DEVI __device__ __forceinline__

typedef __bf16 bf16;
typedef __bf16 bf16x8 __attribute__((ext_vector_type(8)));
typedef __bf16 bf16x4 __attribute__((ext_vector_type(4)));
typedef float  f32x4  __attribute__((ext_vector_type(4)));

static constexpr int T_  = 4096;
static constexpr int H_  = 2048;
static constexpr int KD  = 1024;
static constexpr int VD  = 1024;
static constexpr int OD  = 2048;
static constexpr int CH  = 64;                 // chunk length
static constexpr int NCHUNK = T_ / CH;         // 64
static constexpr int NGROUP = 2;               // chunk groups (ws economy)
static constexpr int CPG    = NCHUNK / NGROUP; // 32

DEVI bf16 tobf(float f) {
  union { float f; uint32_t u; } x; x.f = f;
  uint32_t r = (x.u + 0x7FFFu + ((x.u >> 16) & 1u)) >> 16;  // RNE
  union { uint16_t s; bf16 b; } y; y.s = (uint16_t)r;
  return y.b;
}

DEVI f32x4 fzero() { f32x4 z = {0.f, 0.f, 0.f, 0.f}; return z; }

// async global->LDS, 16B per lane (lane-linear LDS destination).
DEVI void gld16(const bf16* g, bf16* l) {
  auto* g1 = reinterpret_cast<__attribute__((address_space(1))) uint32_t*>(
      (uintptr_t)g);
  auto* l3 = reinterpret_cast<__attribute__((address_space(3))) uint32_t*>(
      (uintptr_t)l);
  __builtin_amdgcn_global_load_lds(g1, l3, 16, 0, 0);
}

template<int N> DEVI void waitvm() {
  if constexpr (N == 0) asm volatile("s_waitcnt vmcnt(0)" ::: "memory");
  else if constexpr (N == 2) asm volatile("s_waitcnt vmcnt(2)" ::: "memory");
  else if constexpr (N == 3) asm volatile("s_waitcnt vmcnt(3)" ::: "memory");
  else if constexpr (N == 4) asm volatile("s_waitcnt vmcnt(4)" ::: "memory");
  else static_assert(N == 0, "unsupported vmcnt");
}

// C[m0..+BM, n0..+BN] += A[M,K] * B[N,K]^T, both row-major K-contiguous.
// 4 waves in 2x2; BK=32; 3-buffer counted pipeline (R5/R7 — best measured).
template<int BM, int BN>
DEVI void gemm_core(const bf16* A, int lda, int m0,
                    const bf16* B, int ldb, int n0,
                    int K, f32x4* acc, bf16* sA, bf16* sB, int tid)
{
  constexpr int MR = BM / 32;
  constexpr int NR = BN / 32;
  constexpr int ASZ = BM * 32;
  constexpr int BSZ = BN * 32;
  constexpr int LOADS = BM / 64 + BN / 64;
  const int lane = tid & 63;
  const int wr = (tid >> 6) >> 1;
  const int wc = (tid >> 6) & 1;
  const int srow = tid >> 2;
  const int skof = (tid & 3) * 8;
  const bf16* aB = A + (size_t)(m0 + srow) * lda + skof;
  const bf16* bB = B + (size_t)(n0 + srow) * ldb + skof;

  auto stage = [&](int t, int buf) {
    const int k0 = t * 32;
#pragma unroll
    for (int r = 0; r < BM / 64; ++r)
      gld16(aB + (size_t)r * 64 * lda + k0, sA + buf * ASZ + r * 2048 + tid * 8);
#pragma unroll
    for (int r = 0; r < BN / 64; ++r)
      gld16(bB + (size_t)r * 64 * ldb + k0, sB + buf * BSZ + r * 2048 + tid * 8);
  };

  const int nt = K / 32;
  stage(0, 0);
  if (nt > 1) stage(1, 1);
  int cur = 0;
  for (int t = 0; t < nt; ++t) {
    if (t < nt - 1) waitvm<LOADS>();
    else            waitvm<0>();
    __builtin_amdgcn_s_barrier();
    __builtin_amdgcn_sched_barrier(0);
    if (t + 2 < nt) {
      int b2 = cur + 2; if (b2 >= 3) b2 -= 3;
      stage(t + 2, b2);
    }
    const bf16* pA = sA + cur * ASZ;
    const bf16* pB = sB + cur * BSZ;
    bf16x8 af[MR], bfr[NR];
#pragma unroll
    for (int m = 0; m < MR; ++m)
      af[m] = *(const bf16x8*)(pA + (wr * (MR * 16) + m * 16 + (lane & 15)) * 32
                               + (lane >> 4) * 8);
#pragma unroll
    for (int n = 0; n < NR; ++n)
      bfr[n] = *(const bf16x8*)(pB + (wc * (NR * 16) + n * 16 + (lane & 15)) * 32
                                + (lane >> 4) * 8);
#pragma unroll
    for (int m = 0; m < MR; ++m)
#pragma unroll
      for (int n = 0; n < NR; ++n)
        acc[m * NR + n] = __builtin_amdgcn_mfma_f32_16x16x32_bf16(
            af[m], bfr[n], acc[m * NR + n], 0, 0, 0);
    ++cur; if (cur >= 3) cur -= 3;
  }
}

// ---------------------------------------------------------------------------
static constexpr size_t CVT_HS = (size_t)T_ * H_;
static constexpr size_t CVT_W  = (size_t)KD * H_;
static constexpr size_t CVT_WO = (size_t)OD * VD;
static constexpr size_t CVT_TOT = CVT_HS + 4 * CVT_W + CVT_WO;

__global__ __launch_bounds__(256) void k_cvt6(
    const float* __restrict__ hs, const float* __restrict__ Wq,
    const float* __restrict__ Wk, const float* __restrict__ Wg,
    const float* __restrict__ Wv, const float* __restrict__ Wo,
    bf16* __restrict__ hsb, bf16* __restrict__ Wqb,
    bf16* __restrict__ Wkb, bf16* __restrict__ Wgb,
    bf16* __restrict__ Wvb, bf16* __restrict__ Wob)
{
  size_t i = ((size_t)blockIdx.x * 256 + threadIdx.x) * 4;
  if (i >= CVT_TOT) return;
  const float* s; bf16* d; size_t off;
  if (i < CVT_HS)                { s = hs; d = hsb; off = i; }
  else if (i < CVT_HS + CVT_W)   { s = Wq; d = Wqb; off = i - CVT_HS; }
  else if (i < CVT_HS + 2*CVT_W) { s = Wk; d = Wkb; off = i - CVT_HS - CVT_W; }
  else if (i < CVT_HS + 3*CVT_W) { s = Wg; d = Wgb; off = i - CVT_HS - 2*CVT_W; }
  else if (i < CVT_HS + 4*CVT_W) { s = Wv; d = Wvb; off = i - CVT_HS - 3*CVT_W; }
  else                           { s = Wo; d = Wob; off = i - CVT_HS - 4*CVT_W; }
  float4 v = *(const float4*)(s + off);
  bf16x4 o; o[0] = tobf(v.x); o[1] = tobf(v.y); o[2] = tobf(v.z); o[3] = tobf(v.w);
  *(bf16x4*)(d + off) = o;
}

// K-split projection GEMM: grid (32 m, 32 nseg, 2 kh); bf16 partials.
// m0-fast dispatch order keeps each XCD's hs slice L2-resident (R10 lesson).
__global__ __launch_bounds__(256) void k_projA(
    const bf16* __restrict__ hsb,
    const bf16* __restrict__ Wqb, const bf16* __restrict__ Wkb,
    const bf16* __restrict__ Wgb, const bf16* __restrict__ Wvb,
    bf16* __restrict__ pbuf)
{
  __shared__ __align__(16) bf16 sA[3 * 128 * 32];
  __shared__ __align__(16) bf16 sB[3 * 128 * 32];
  const int m0 = blockIdx.x * 128;
  const int nseg = blockIdx.y;          // 0..31
  const int kh = blockIdx.z;            // 0..1
  const int seg = nseg >> 3;
  const int n0 = (nseg & 7) * 128;
  const bf16* W = seg == 0 ? Wqb : seg == 1 ? Wkb : seg == 2 ? Wgb : Wvb;
  const int tid = threadIdx.x, lane = tid & 63;
  const int wr = (tid >> 6) >> 1, wc = (tid >> 6) & 1;
  f32x4 acc[16];
#pragma unroll
  for (int i = 0; i < 16; ++i) acc[i] = fzero();
  gemm_core<128, 128>(hsb + kh * 1024, H_, m0, W + kh * 1024, H_, n0, 1024,
                      acc, sA, sB, tid);
  bf16* dst = pbuf + (size_t)kh * T_ * 4096;
#pragma unroll
  for (int m = 0; m < 4; ++m)
#pragma unroll
    for (int n = 0; n < 4; ++n) {
      f32x4 v = acc[m * 4 + n];
      int colF = seg * 1024 + n0 + wc * 64 + n * 16 + (lane & 15);
#pragma unroll
      for (int r = 0; r < 4; ++r) {
        int row = m0 + wr * 64 + m * 16 + (lane >> 4) * 4 + r;
        dst[(size_t)row * 4096 + colF] = tobf(v[r]);
      }
    }
}

// reduce partials + bias + activations -> qb / kb / la / vb
__global__ __launch_bounds__(256) void k_projB(
    const bf16* __restrict__ pbuf,
    const float* __restrict__ bq, const float* __restrict__ bk,
    const float* __restrict__ bg, const float* __restrict__ bv,
    bf16* __restrict__ qb, bf16* __restrict__ kb,
    float* __restrict__ la, bf16* __restrict__ vb)
{
  size_t i = ((size_t)blockIdx.x * 256 + threadIdx.x) * 8;   // over T_*4096
  int row = (int)(i >> 12), colF = (int)(i & 4095);
  int seg = colF >> 10, col = colF & 1023;
  bf16x8 p0 = *(const bf16x8*)(pbuf + i);
  bf16x8 p1 = *(const bf16x8*)(pbuf + (size_t)T_ * 4096 + i);
  const float* bias = seg == 0 ? bq : seg == 1 ? bk : seg == 2 ? bg : bv;
  float4 b0 = *(const float4*)(bias + col);
  float4 b1 = *(const float4*)(bias + col + 4);
  float x[8];
#pragma unroll
  for (int j = 0; j < 8; ++j) {
    float b = j < 4 ? (&b0.x)[j] : (&b1.x)[j - 4];
    x[j] = (float)p0[j] + (float)p1[j] + b;
  }
  size_t o = (size_t)row * KD + col;
  if (seg == 2) {
    float4 o0, o1;
#pragma unroll
    for (int j = 0; j < 4; ++j)
      (&o0.x)[j] = fminf(x[j], 0.f) - log1pf(expf(-fabsf(x[j])));
#pragma unroll
    for (int j = 0; j < 4; ++j)
      (&o1.x)[j] = fminf(x[4 + j], 0.f) - log1pf(expf(-fabsf(x[4 + j])));
    *(float4*)(la + o) = o0; *(float4*)(la + o + 4) = o1;
  } else {
    bf16x8 ov;
#pragma unroll
    for (int j = 0; j < 8; ++j) {
      float y = (seg == 1) ? 1.f / (1.f + expf(-x[j])) : x[j];
      ov[j] = tobf(y);
    }
    bf16* dst = seg == 0 ? qb : seg == 1 ? kb : vb;
    *(bf16x8*)(dst + o) = ov;
  }
}

// path0: fused within-chunk prefix of log g + decay-weighted operands.
// path1: V^T [c][vv][t].
__global__ __launch_bounds__(256) void k_transform(
    const bf16* __restrict__ qb, const bf16* __restrict__ kb,
    const float* __restrict__ la, const bf16* __restrict__ vb,
    bf16* __restrict__ qt, bf16* __restrict__ kt,
    bf16* __restrict__ kbarT, bf16* __restrict__ vT,
    float* __restrict__ laC)
{
  __shared__ bf16 tr[64][72];
  __shared__ float gtot[4][64];
  const int c = blockIdx.y, tile = blockIdx.x, path = blockIdx.z;
  const int tid = threadIdx.x;
  const int colL = tid & 63;
  const int grp = tid >> 6;            // 0..3
  if (path == 0) {
    const int kk0 = tile * 64;
    const int kk = kk0 + colL;
    float lraw[16];
    float run = 0.f;
#pragma unroll
    for (int i = 0; i < 16; ++i) {
      int t = grp * 16 + i;
      lraw[i] = la[(size_t)(c * CH + t) * KD + kk];
      run += lraw[i];
    }
    gtot[grp][colL] = run;
    __syncthreads();
    float off = 0.f, lc = 0.f;
#pragma unroll
    for (int g2 = 0; g2 < 4; ++g2) {
      float v = gtot[g2][colL];
      if (g2 < grp) off += v;
      lc += v;
    }
    if (grp == 0) laC[(size_t)c * KD + kk] = lc;
    float run2 = off;
#pragma unroll
    for (int i = 0; i < 16; ++i) {
      int t = grp * 16 + i;
      run2 += lraw[i];
      size_t idx = (size_t)(c * CH + t) * KD + kk;
      float qv = (float)qb[idx];
      float kv = (float)kb[idx];
      qt[idx] = tobf(qv * expf(run2));
      kt[idx] = tobf(kv * expf(-run2));
      tr[colL][t] = tobf(kv * expf(lc - run2));   // kbar, staged for transpose
    }
    __syncthreads();
#pragma unroll
    for (int i = 0; i < 16; ++i) {
      int row = grp + 4 * i;
      kbarT[((size_t)c * KD + kk0 + row) * 64 + colL] = tr[row][colL];
    }
  } else {
    const int vv0 = tile * 64;
#pragma unroll
    for (int i = 0; i < 16; ++i) {
      int t = grp + 4 * i;
      tr[colL][t] = vb[(size_t)(c * CH + t) * VD + vv0 + colL];
    }
    __syncthreads();
#pragma unroll
    for (int i = 0; i < 16; ++i) {
      int row = grp + 4 * i;
      vT[((size_t)c * VD + vv0 + row) * 64 + colL] = tr[row][colL];
    }
  }
}

// K-split QK^T partials body: Ppart[c][ks] = q~ slice @ k~ slice^T (fp32)
DEVI void qkt_body(const bf16* __restrict__ qt, const bf16* __restrict__ kt,
                   float* __restrict__ Ppart, int ks, int c, int tid)
{
  __shared__ __align__(16) bf16 sAq[3 * 64 * 32];
  __shared__ __align__(16) bf16 sBq[3 * 64 * 32];
  const int lane = tid & 63;
  const int wr = (tid >> 6) >> 1, wc = (tid >> 6) & 1;
  f32x4 acc[4];
#pragma unroll
  for (int i = 0; i < 4; ++i) acc[i] = fzero();
  gemm_core<64, 64>(qt + (size_t)c * CH * KD + ks * 256, KD, 0,
                    kt + (size_t)c * CH * KD + ks * 256, KD, 0, 256,
                    acc, sAq, sBq, tid);
  float* dst = Ppart + ((size_t)c * 4 + ks) * 4096;
#pragma unroll
  for (int m = 0; m < 2; ++m)
#pragma unroll
    for (int n = 0; n < 2; ++n) {
      f32x4 v = acc[m * 2 + n];
      int j = wc * 32 + n * 16 + (lane & 15);
#pragma unroll
      for (int r = 0; r < 4; ++r) {
        int t = wr * 32 + m * 16 + (lane >> 4) * 4 + r;
        dst[t * 64 + j] = v[r];
      }
    }
}

// fused U-GEMM + decay scan body (S in MFMA accumulator, fp32 across chunks).
// R9 version: direct (scalar) S_c stores — R11 showed the LDS restage regresses.
DEVI void uscan_body(const bf16* __restrict__ vT, const bf16* __restrict__ kbarT,
                     const float* __restrict__ laC, bf16* __restrict__ Sstore,
                     float* __restrict__ Sinit, bf16* __restrict__ ScarryB,
                     float* __restrict__ dstate, int g, int bx, int by, int tid)
{
  __shared__ __align__(16) bf16 sAu[3 * 4096];  // [buf][ks*2048 + row*32 + kof]
  __shared__ __align__(16) bf16 sBu[3 * 4096];
  const int vv0 = bx * 64, kk0 = by * 64;
  const int lane = tid & 63;
  const int wr = (tid >> 6) >> 1, wc = (tid >> 6) & 1;
  const int srow = tid >> 2, skof = (tid & 3) * 8;

  auto stage = [&](int cl, int buf) {
    const int c = g * CPG + cl;
    const bf16* vP = vT + ((size_t)c * VD + vv0 + srow) * 64 + skof;
    const bf16* kP = kbarT + ((size_t)c * KD + kk0 + srow) * 64 + skof;
    gld16(vP,      sAu + buf * 4096 + tid * 8);
    gld16(vP + 32, sAu + buf * 4096 + 2048 + tid * 8);
    gld16(kP,      sBu + buf * 4096 + tid * 8);
    gld16(kP + 32, sBu + buf * 4096 + 2048 + tid * 8);
  };

  const int col0 = kk0 + wc * 32 + (lane & 15);
  const int row0 = vv0 + wr * 32 + (lane >> 4) * 4;

  f32x4 S[4];
  if (g == 0) {
#pragma unroll
    for (int i = 0; i < 4; ++i) S[i] = fzero();
  } else {
#pragma unroll
    for (int m = 0; m < 2; ++m)
#pragma unroll
      for (int n = 0; n < 2; ++n)
#pragma unroll
        for (int r = 0; r < 4; ++r)
          S[m * 2 + n][r] =
              Sinit[(size_t)(row0 + m * 16 + r) * KD + col0 + n * 16];
  }

  stage(0, 0);
  stage(1, 1);
  float ln0 = laC[(size_t)(g * CPG) * KD + col0];
  float ln1 = laC[(size_t)(g * CPG) * KD + col0 + 16];

  for (int cl = 0; cl < CPG; ++cl) {
    if (cl < CPG - 1) waitvm<4>();
    else              waitvm<0>();
    __builtin_amdgcn_s_barrier();
    __builtin_amdgcn_sched_barrier(0);
    const float d0 = expf(ln0), d1 = expf(ln1);
#pragma unroll
    for (int m = 0; m < 2; ++m)
#pragma unroll
      for (int r = 0; r < 4; ++r) {
        S[m * 2 + 0][r] *= d0;
        S[m * 2 + 1][r] *= d1;
      }
    int buf = cl % 3;
    const bf16* pA = sAu + buf * 4096;
    const bf16* pB = sBu + buf * 4096;
#pragma unroll
    for (int ks = 0; ks < 2; ++ks) {
      bf16x8 af[2], bfr[2];
#pragma unroll
      for (int m = 0; m < 2; ++m)
        af[m] = *(const bf16x8*)(pA + ks * 2048
                 + (wr * 32 + m * 16 + (lane & 15)) * 32 + (lane >> 4) * 8);
#pragma unroll
      for (int n = 0; n < 2; ++n)
        bfr[n] = *(const bf16x8*)(pB + ks * 2048
                 + (wc * 32 + n * 16 + (lane & 15)) * 32 + (lane >> 4) * 8);
#pragma unroll
      for (int m = 0; m < 2; ++m)
#pragma unroll
        for (int n = 0; n < 2; ++n)
          S[m * 2 + n] = __builtin_amdgcn_mfma_f32_16x16x32_bf16(
              af[m], bfr[n], S[m * 2 + n], 0, 0, 0);
    }
    // write S_c (bf16); stores precede next stage() so waitvm<4> counts only
    // the 4 prefetch loads.
    bf16* dst = Sstore + (size_t)cl * KD * VD;
#pragma unroll
    for (int m = 0; m < 2; ++m)
#pragma unroll
      for (int n = 0; n < 2; ++n)
#pragma unroll
        for (int r = 0; r < 4; ++r)
          dst[(size_t)(row0 + m * 16 + r) * KD + col0 + n * 16] =
              tobf(S[m * 2 + n][r]);
    if (cl + 1 < CPG) {
      ln0 = laC[(size_t)(g * CPG + cl + 1) * KD + col0];
      ln1 = laC[(size_t)(g * CPG + cl + 1) * KD + col0 + 16];
    }
    if (cl + 2 < CPG) stage(cl + 2, (cl + 2) % 3);
  }

  if (g < NGROUP - 1) {
#pragma unroll
    for (int m = 0; m < 2; ++m)
#pragma unroll
      for (int n = 0; n < 2; ++n)
#pragma unroll
        for (int r = 0; r < 4; ++r) {
          size_t o = (size_t)(row0 + m * 16 + r) * KD + col0 + n * 16;
          Sinit[o] = S[m * 2 + n][r];
          ScarryB[o] = tobf(S[m * 2 + n][r]);
        }
  } else {
    // final state -> dstate [kk][vv] via LDS transpose (reuse sAu as fp32)
    float* flds = (float*)sAu;               // 64x65 fp32 = 16.6KB < 24KB
    __syncthreads();
#pragma unroll
    for (int m = 0; m < 2; ++m)
#pragma unroll
      for (int n = 0; n < 2; ++n)
#pragma unroll
        for (int r = 0; r < 4; ++r)
          flds[(wr * 32 + m * 16 + (lane >> 4) * 4 + r) * 65
               + wc * 32 + n * 16 + (lane & 15)] = S[m * 2 + n][r];
    __syncthreads();
    const int kkL = tid & 63;
    const int vb0 = (tid >> 6) * 16;
    float* dp = dstate + (size_t)(kk0 + kkL) * VD + vv0 + vb0;
#pragma unroll
    for (int q = 0; q < 4; ++q) {
      float4 o = {flds[(vb0 + q * 4 + 0) * 65 + kkL],
                  flds[(vb0 + q * 4 + 1) * 65 + kkL],
                  flds[(vb0 + q * 4 + 2) * 65 + kkL],
                  flds[(vb0 + q * 4 + 3) * 65 + kkL]};
      *(float4*)(dp + q * 4) = o;
    }
  }
}

// union kernel: z=0 -> qkt (256 blocks), z=1 -> uscan g=0 (256 blocks).
// Both independent; co-resident at 2 blocks/CU so qkt's MFMA work hides the
// scan's serial-chain latency.
__global__ __launch_bounds__(256) void k_qkt_uscan(
    const bf16* __restrict__ qt, const bf16* __restrict__ kt,
    float* __restrict__ Ppart,
    const bf16* __restrict__ vT, const bf16* __restrict__ kbarT,
    const float* __restrict__ laC, bf16* __restrict__ Sstore,
    float* __restrict__ Sinit, bf16* __restrict__ ScarryB,
    float* __restrict__ dstate)
{
  const int tid = threadIdx.x;
  if (blockIdx.z == 0) {
    const int flat = blockIdx.x + 16 * blockIdx.y;   // 0..255
    qkt_body(qt, kt, Ppart, flat & 3, flat >> 2, tid);
  } else {
    uscan_body(vT, kbarT, laC, Sstore, Sinit, ScarryB, dstate, 0,
               blockIdx.x, blockIdx.y, tid);
  }
}

// standalone uscan for g=1
__global__ __launch_bounds__(256) void k_uscan(
    const bf16* __restrict__ vT, const bf16* __restrict__ kbarT,
    const float* __restrict__ laC, bf16* __restrict__ Sstore,
    float* __restrict__ Sinit, bf16* __restrict__ ScarryB,
    float* __restrict__ dstate, int g)
{
  uscan_body(vT, kbarT, laC, Sstore, Sinit, ScarryB, dstate, g,
             blockIdx.x, blockIdx.y, threadIdx.x);
}

// fused: P assemble + inter GEMM (q~_c @ S_{c-1}) + PV (128-col slice)
// -> ob = bf16(intra + inter). grid (8 ntiles, CPG chunks).
__global__ __launch_bounds__(256) void k_inter2(
    const bf16* __restrict__ qt, const float* __restrict__ Ppart,
    const bf16* __restrict__ vT, const bf16* __restrict__ Sstore,
    const bf16* __restrict__ ScarryB, bf16* __restrict__ ob, int g)
{
  __shared__ __align__(16) bf16 sA[3 * 64 * 32];
  __shared__ __align__(16) bf16 sB[3 * 128 * 32];
  __shared__ __align__(16) bf16 Pl[64 * 72];
  __shared__ __align__(16) bf16 sV[128 * 72];
  const int cl = blockIdx.y, c = g * CPG + cl;
  const int n0 = blockIdx.x * 128;
  const int tid = threadIdx.x, lane = tid & 63;
  const int wr = (tid >> 6) >> 1, wc = (tid >> 6) & 1;

  // assemble P = sum of 4 K-partials, causal mask, bf16 into Pl
  {
    const float* base = Ppart + (size_t)c * 4 * 4096;
    const int i0 = tid * 16;
    const int t = tid >> 2;
    const int j0 = (tid & 3) * 16;
#pragma unroll
    for (int e = 0; e < 16; e += 4) {
      float4 s0 = *(const float4*)(base + 0 * 4096 + i0 + e);
      float4 s1 = *(const float4*)(base + 1 * 4096 + i0 + e);
      float4 s2 = *(const float4*)(base + 2 * 4096 + i0 + e);
      float4 s3 = *(const float4*)(base + 3 * 4096 + i0 + e);
      float sx = s0.x + s1.x + s2.x + s3.x;
      float sy = s0.y + s1.y + s2.y + s3.y;
      float sz = s0.z + s1.z + s2.z + s3.z;
      float sw = s0.w + s1.w + s2.w + s3.w;
      int j = j0 + e;
      Pl[t * 72 + j + 0] = (j + 0 <= t) ? tobf(sx) : tobf(0.f);
      Pl[t * 72 + j + 1] = (j + 1 <= t) ? tobf(sy) : tobf(0.f);
      Pl[t * 72 + j + 2] = (j + 2 <= t) ? tobf(sz) : tobf(0.f);
      Pl[t * 72 + j + 3] = (j + 3 <= t) ? tobf(sw) : tobf(0.f);
    }
  }
  __syncthreads();

  f32x4 acc[8];
#pragma unroll
  for (int i = 0; i < 8; ++i) acc[i] = fzero();
  if (c > 0) {
    const bf16* B = (cl == 0) ? ScarryB : Sstore + (size_t)(cl - 1) * KD * VD;
    gemm_core<64, 128>(qt + (size_t)c * CH * KD, KD, 0, B, KD, n0, KD,
                       acc, sA, sB, tid);
  }

  // stage V^T slice rows [n0, n0+128) and add PV into acc
#pragma unroll
  for (int rr = 0; rr < 4; ++rr) {
    int row = rr * 32 + (tid >> 3);
    int j0 = (tid & 7) * 8;
    bf16x8 vv = *(const bf16x8*)(vT + ((size_t)c * VD + n0 + row) * 64 + j0);
    *(bf16x8*)(sV + row * 72 + j0) = vv;
  }
  __syncthreads();
#pragma unroll
  for (int ks = 0; ks < 64; ks += 32) {
    bf16x8 af[2], bfr[4];
#pragma unroll
    for (int m = 0; m < 2; ++m)
      af[m] = *(const bf16x8*)(Pl + (wr * 32 + m * 16 + (lane & 15)) * 72
                               + ks + (lane >> 4) * 8);
#pragma unroll
    for (int n = 0; n < 4; ++n)
      bfr[n] = *(const bf16x8*)(sV + (wc * 64 + n * 16 + (lane & 15)) * 72
                                + ks + (lane >> 4) * 8);
#pragma unroll
    for (int m = 0; m < 2; ++m)
#pragma unroll
      for (int n = 0; n < 4; ++n)
        acc[m * 4 + n] = __builtin_amdgcn_mfma_f32_16x16x32_bf16(
            af[m], bfr[n], acc[m * 4 + n], 0, 0, 0);
  }

#pragma unroll
  for (int m = 0; m < 2; ++m)
#pragma unroll
    for (int n = 0; n < 4; ++n) {
      f32x4 v = acc[m * 4 + n];
      int col = wc * 64 + n * 16 + (lane & 15);
#pragma unroll
      for (int r = 0; r < 4; ++r) {
        int row = wr * 32 + m * 16 + (lane >> 4) * 4 + r;
        ob[((size_t)c * CH + row) * VD + n0 + col] = tobf(v[r]);
      }
    }
}

// y = ob @ Wo^T + bo. BN=64: grid (32, 32) = 1024 blocks, 4/CU.
__global__ __launch_bounds__(256) void k_out(
    const bf16* __restrict__ ob, const bf16* __restrict__ Wob,
    const float* __restrict__ bo, float* __restrict__ out)
{
  __shared__ __align__(16) bf16 sA[3 * 128 * 32];
  __shared__ __align__(16) bf16 sB[3 * 64 * 32];
  const int m0 = blockIdx.x * 128, n0 = blockIdx.y * 64;
  const int tid = threadIdx.x, lane = tid & 63;
  const int wr = (tid >> 6) >> 1, wc = (tid >> 6) & 1;
  f32x4 acc[8];
#pragma unroll
  for (int i = 0; i < 8; ++i) acc[i] = fzero();
  gemm_core<128, 64>(ob, VD, m0, Wob, VD, n0, VD, acc, sA, sB, tid);
#pragma unroll
  for (int m = 0; m < 4; ++m)
#pragma unroll
    for (int n = 0; n < 2; ++n) {
      f32x4 v = acc[m * 2 + n];
      int col = n0 + wc * 32 + n * 16 + (lane & 15);
      float b = bo[col];
#pragma unroll
      for (int r = 0; r < 4; ++r) {
        int row = m0 + wr * 64 + m * 16 + (lane >> 4) * 4 + r;
        out[(size_t)row * OD + col] = v[r] + b;
      }
    }
}

// ---------------------------------------------------------------------------
extern "C" void kernel_launch(void* const* d_in, const int* in_sizes, int n_in,
                              void* d_out, int out_size, void* d_ws, size_t ws_size,
                              hipStream_t stream)
{
  const float* hs = (const float*)d_in[0];
  const float* Wq = (const float*)d_in[1];
  const float* bq = (const float*)d_in[2];
  const float* Wk = (const float*)d_in[3];
  const float* bk = (const float*)d_in[4];
  const float* Wv = (const float*)d_in[5];
  const float* bv = (const float*)d_in[6];
  const float* Wg = (const float*)d_in[7];
  const float* bg = (const float*)d_in[8];
  const float* Wo = (const float*)d_in[9];
  const float* bo = (const float*)d_in[10];
  float* out = (float*)d_out;
  float* dstate = out + (size_t)T_ * OD;

  char* p = (char*)d_ws;
  auto alloc = [&](size_t b) -> char* {
    char* r = p; p += (b + 255) & ~(size_t)255; return r;
  };
  bf16* hsb    = (bf16*)alloc((size_t)T_ * H_ * 2);
  bf16* Wqb    = (bf16*)alloc((size_t)KD * H_ * 2);
  bf16* Wkb    = (bf16*)alloc((size_t)KD * H_ * 2);
  bf16* Wgb    = (bf16*)alloc((size_t)KD * H_ * 2);
  bf16* Wvb    = (bf16*)alloc((size_t)VD * H_ * 2);
  bf16* Wob    = (bf16*)alloc((size_t)OD * VD * 2);
  bf16* qb     = (bf16*)alloc((size_t)T_ * KD * 2);
  bf16* kb     = (bf16*)alloc((size_t)T_ * KD * 2);
  float* la    = (float*)alloc((size_t)T_ * KD * 4);
  bf16* vb     = (bf16*)alloc((size_t)T_ * VD * 2);
  bf16* qt     = (bf16*)alloc((size_t)T_ * KD * 2);
  bf16* kt     = (bf16*)alloc((size_t)T_ * KD * 2);
  bf16* kbarT  = (bf16*)alloc((size_t)T_ * KD * 2);
  bf16* vT     = (bf16*)alloc((size_t)T_ * VD * 2);
  bf16* ob     = (bf16*)alloc((size_t)T_ * VD * 2);
  float* Sinit = (float*)alloc((size_t)KD * VD * 4);
  bf16* ScarryB= (bf16*)alloc((size_t)KD * VD * 2);
  bf16* Sstore = (bf16*)alloc((size_t)CPG * KD * VD * 2);   // 64 MB
  float* laC   = (float*)alloc((size_t)NCHUNK * KD * 4);
  float* Ppart = (float*)alloc((size_t)NCHUNK * 4 * 4096 * 4);
  if ((size_t)(p - (char*)d_ws) > ws_size) return;

  // pbuf (proj partials, 64MB bf16) reuses Sstore: free until first uscan.
  bf16* pbuf = Sstore;

  k_cvt6<<<(int)((CVT_TOT / 4 + 255) / 256), 256, 0, stream>>>(
      hs, Wq, Wk, Wg, Wv, Wo, hsb, Wqb, Wkb, Wgb, Wvb, Wob);

  k_projA<<<dim3(T_ / 128, 32, 2), 256, 0, stream>>>(
      hsb, Wqb, Wkb, Wgb, Wvb, pbuf);
  k_projB<<<(int)((size_t)T_ * 4096 / 8 / 256), 256, 0, stream>>>(
      pbuf, bq, bk, bg, bv, qb, kb, la, vb);

  k_transform<<<dim3(16, NCHUNK, 2), 256, 0, stream>>>(
      qb, kb, la, vb, qt, kt, kbarT, vT, laC);

  // co-scheduled: qkt (z=0) + uscan g=0 (z=1)
  k_qkt_uscan<<<dim3(16, 16, 2), 256, 0, stream>>>(
      qt, kt, Ppart, vT, kbarT, laC, Sstore, Sinit, ScarryB, dstate);

  k_inter2<<<dim3(8, CPG), 256, 0, stream>>>(
      qt, Ppart, vT, Sstore, ScarryB, ob, 0);
  k_uscan<<<dim3(16, 16), 256, 0, stream>>>(
      vT, kbarT, laC, Sstore, Sinit, ScarryB, dstate, 1);
  k_inter2<<<dim3(8, CPG), 256, 0, stream>>>(
      qt, Ppart, vT, Sstore, ScarryB, ob, 1);

  k_out<<<dim3(T_ / 128, OD / 64), 256, 0, stream>>>(ob, Wob, bo, out);
}

// Round 13
// 274.612 us; speedup vs baseline: 1.1120x; 1.0459x over previous
//
#include <hip/hip_runtime.h>
#include <stdint.h>
#include <stddef.h>

// ---------------------------------------------------------------------------
// SimpleRNN (gated linear attention) — chunked parallel formulation.
//   q = hs@Wq^T+bq ; k = sig(hs@Wk^T+bk) ; g = sig(hs@Wg^T+bg) ; v = hs@Wv^T+bv
//   S_t = diag(g_t) S_{t-1} + k_t v_t^T ; out_t = q_t S_t ; y = out@Wo^T+bo
// Chunked (C=64): la = within-chunk cumsum(log g), q~ = q*exp(la),
//   k~ = k*exp(-la), kbar = k*exp(laC-la)
//   out = tril(q~ k~^T) V  +  q~ @ S_prev
//   U_c = kbar^T V ;  S_c = exp(laC) (.) S_{c-1} + U_c
//
// R13 = R12 + projB fused into transform (k_ptrans): reads projA's bf16
// K-half partials directly, applies bias+activations in-register, runs the
// chunk prefix, emits qt/kt/kbarT/vT/laC. Eliminates the qb/kb/la/vb 40MB
// intermediate (80MB round-trip) and one launch.
// ---------------------------------------------------------------------------

#define DEVI __device__ __forceinline__

typedef __bf16 bf16;
typedef __bf16 bf16x8 __attribute__((ext_vector_type(8)));
typedef __bf16 bf16x4 __attribute__((ext_vector_type(4)));
typedef float  f32x4  __attribute__((ext_vector_type(4)));

static constexpr int T_  = 4096;
static constexpr int H_  = 2048;
static constexpr int KD  = 1024;
static constexpr int VD  = 1024;
static constexpr int OD  = 2048;
static constexpr int CH  = 64;                 // chunk length
static constexpr int NCHUNK = T_ / CH;         // 64
static constexpr int NGROUP = 2;               // chunk groups (ws economy)
static constexpr int CPG    = NCHUNK / NGROUP; // 32

DEVI bf16 tobf(float f) {
  union { float f; uint32_t u; } x; x.f = f;
  uint32_t r = (x.u + 0x7FFFu + ((x.u >> 16) & 1u)) >> 16;  // RNE
  union { uint16_t s; bf16 b; } y; y.s = (uint16_t)r;
  return y.b;
}

DEVI f32x4 fzero() { f32x4 z = {0.f, 0.f, 0.f, 0.f}; return z; }

// async global->LDS, 16B per lane (lane-linear LDS destination).
DEVI void gld16(const bf16* g, bf16* l) {
  auto* g1 = reinterpret_cast<__attribute__((address_space(1))) uint32_t*>(
      (uintptr_t)g);
  auto* l3 = reinterpret_cast<__attribute__((address_space(3))) uint32_t*>(
      (uintptr_t)l);
  __builtin_amdgcn_global_load_lds(g1, l3, 16, 0, 0);
}

template<int N> DEVI void waitvm() {
  if constexpr (N == 0) asm volatile("s_waitcnt vmcnt(0)" ::: "memory");
  else if constexpr (N == 2) asm volatile("s_waitcnt vmcnt(2)" ::: "memory");
  else if constexpr (N == 3) asm volatile("s_waitcnt vmcnt(3)" ::: "memory");
  else if constexpr (N == 4) asm volatile("s_waitcnt vmcnt(4)" ::: "memory");
  else static_assert(N == 0, "unsupported vmcnt");
}

// C[m0..+BM, n0..+BN] += A[M,K] * B[N,K]^T, both row-major K-contiguous.
// 4 waves in 2x2; BK=32; 3-buffer counted pipeline (R5/R7 — best measured).
template<int BM, int BN>
DEVI void gemm_core(const bf16* A, int lda, int m0,
                    const bf16* B, int ldb, int n0,
                    int K, f32x4* acc, bf16* sA, bf16* sB, int tid)
{
  constexpr int MR = BM / 32;
  constexpr int NR = BN / 32;
  constexpr int ASZ = BM * 32;
  constexpr int BSZ = BN * 32;
  constexpr int LOADS = BM / 64 + BN / 64;
  const int lane = tid & 63;
  const int wr = (tid >> 6) >> 1;
  const int wc = (tid >> 6) & 1;
  const int srow = tid >> 2;
  const int skof = (tid & 3) * 8;
  const bf16* aB = A + (size_t)(m0 + srow) * lda + skof;
  const bf16* bB = B + (size_t)(n0 + srow) * ldb + skof;

  auto stage = [&](int t, int buf) {
    const int k0 = t * 32;
#pragma unroll
    for (int r = 0; r < BM / 64; ++r)
      gld16(aB + (size_t)r * 64 * lda + k0, sA + buf * ASZ + r * 2048 + tid * 8);
#pragma unroll
    for (int r = 0; r < BN / 64; ++r)
      gld16(bB + (size_t)r * 64 * ldb + k0, sB + buf * BSZ + r * 2048 + tid * 8);
  };

  const int nt = K / 32;
  stage(0, 0);
  if (nt > 1) stage(1, 1);
  int cur = 0;
  for (int t = 0; t < nt; ++t) {
    if (t < nt - 1) waitvm<LOADS>();
    else            waitvm<0>();
    __builtin_amdgcn_s_barrier();
    __builtin_amdgcn_sched_barrier(0);
    if (t + 2 < nt) {
      int b2 = cur + 2; if (b2 >= 3) b2 -= 3;
      stage(t + 2, b2);
    }
    const bf16* pA = sA + cur * ASZ;
    const bf16* pB = sB + cur * BSZ;
    bf16x8 af[MR], bfr[NR];
#pragma unroll
    for (int m = 0; m < MR; ++m)
      af[m] = *(const bf16x8*)(pA + (wr * (MR * 16) + m * 16 + (lane & 15)) * 32
                               + (lane >> 4) * 8);
#pragma unroll
    for (int n = 0; n < NR; ++n)
      bfr[n] = *(const bf16x8*)(pB + (wc * (NR * 16) + n * 16 + (lane & 15)) * 32
                                + (lane >> 4) * 8);
#pragma unroll
    for (int m = 0; m < MR; ++m)
#pragma unroll
      for (int n = 0; n < NR; ++n)
        acc[m * NR + n] = __builtin_amdgcn_mfma_f32_16x16x32_bf16(
            af[m], bfr[n], acc[m * NR + n], 0, 0, 0);
    ++cur; if (cur >= 3) cur -= 3;
  }
}

// ---------------------------------------------------------------------------
static constexpr size_t CVT_HS = (size_t)T_ * H_;
static constexpr size_t CVT_W  = (size_t)KD * H_;
static constexpr size_t CVT_WO = (size_t)OD * VD;
static constexpr size_t CVT_TOT = CVT_HS + 4 * CVT_W + CVT_WO;

__global__ __launch_bounds__(256) void k_cvt6(
    const float* __restrict__ hs, const float* __restrict__ Wq,
    const float* __restrict__ Wk, const float* __restrict__ Wg,
    const float* __restrict__ Wv, const float* __restrict__ Wo,
    bf16* __restrict__ hsb, bf16* __restrict__ Wqb,
    bf16* __restrict__ Wkb, bf16* __restrict__ Wgb,
    bf16* __restrict__ Wvb, bf16* __restrict__ Wob)
{
  size_t i = ((size_t)blockIdx.x * 256 + threadIdx.x) * 4;
  if (i >= CVT_TOT) return;
  const float* s; bf16* d; size_t off;
  if (i < CVT_HS)                { s = hs; d = hsb; off = i; }
  else if (i < CVT_HS + CVT_W)   { s = Wq; d = Wqb; off = i - CVT_HS; }
  else if (i < CVT_HS + 2*CVT_W) { s = Wk; d = Wkb; off = i - CVT_HS - CVT_W; }
  else if (i < CVT_HS + 3*CVT_W) { s = Wg; d = Wgb; off = i - CVT_HS - 2*CVT_W; }
  else if (i < CVT_HS + 4*CVT_W) { s = Wv; d = Wvb; off = i - CVT_HS - 3*CVT_W; }
  else                           { s = Wo; d = Wob; off = i - CVT_HS - 4*CVT_W; }
  float4 v = *(const float4*)(s + off);
  bf16x4 o; o[0] = tobf(v.x); o[1] = tobf(v.y); o[2] = tobf(v.z); o[3] = tobf(v.w);
  *(bf16x4*)(d + off) = o;
}

// K-split projection GEMM: grid (32 m, 32 nseg, 2 kh); bf16 partials.
// m0-fast dispatch order keeps each XCD's hs slice L2-resident (R10 lesson).
__global__ __launch_bounds__(256) void k_projA(
    const bf16* __restrict__ hsb,
    const bf16* __restrict__ Wqb, const bf16* __restrict__ Wkb,
    const bf16* __restrict__ Wgb, const bf16* __restrict__ Wvb,
    bf16* __restrict__ pbuf)
{
  __shared__ __align__(16) bf16 sA[3 * 128 * 32];
  __shared__ __align__(16) bf16 sB[3 * 128 * 32];
  const int m0 = blockIdx.x * 128;
  const int nseg = blockIdx.y;          // 0..31
  const int kh = blockIdx.z;            // 0..1
  const int seg = nseg >> 3;
  const int n0 = (nseg & 7) * 128;
  const bf16* W = seg == 0 ? Wqb : seg == 1 ? Wkb : seg == 2 ? Wgb : Wvb;
  const int tid = threadIdx.x, lane = tid & 63;
  const int wr = (tid >> 6) >> 1, wc = (tid >> 6) & 1;
  f32x4 acc[16];
#pragma unroll
  for (int i = 0; i < 16; ++i) acc[i] = fzero();
  gemm_core<128, 128>(hsb + kh * 1024, H_, m0, W + kh * 1024, H_, n0, 1024,
                      acc, sA, sB, tid);
  bf16* dst = pbuf + (size_t)kh * T_ * 4096;
#pragma unroll
  for (int m = 0; m < 4; ++m)
#pragma unroll
    for (int n = 0; n < 4; ++n) {
      f32x4 v = acc[m * 4 + n];
      int colF = seg * 1024 + n0 + wc * 64 + n * 16 + (lane & 15);
#pragma unroll
      for (int r = 0; r < 4; ++r) {
        int row = m0 + wr * 64 + m * 16 + (lane >> 4) * 4 + r;
        dst[(size_t)row * 4096 + colF] = tobf(v[r]);
      }
    }
}

// fused projB + transform: read K-half partials, bias+activations, chunk
// prefix, emit qt/kt/kbarT/vT/laC. path0 = q/k/g columns, path1 = v columns.
__global__ __launch_bounds__(256) void k_ptrans(
    const bf16* __restrict__ pbuf,
    const float* __restrict__ bq, const float* __restrict__ bk,
    const float* __restrict__ bg, const float* __restrict__ bv,
    bf16* __restrict__ qt, bf16* __restrict__ kt,
    bf16* __restrict__ kbarT, bf16* __restrict__ vT,
    float* __restrict__ laC)
{
  __shared__ bf16 tr[64][72];
  __shared__ float gtot[4][64];
  const int c = blockIdx.y, tile = blockIdx.x, path = blockIdx.z;
  const int tid = threadIdx.x;
  const int colL = tid & 63;
  const int grp = tid >> 6;            // 0..3
  const bf16* pb0 = pbuf;
  const bf16* pb1 = pbuf + (size_t)T_ * 4096;
  if (path == 0) {
    const int kk0 = tile * 64;
    const int kk = kk0 + colL;
    const float bqv = bq[kk], bkv = bk[kk], bgv = bg[kk];
    float qv[16], kv[16], lraw[16];
    float run = 0.f;
#pragma unroll
    for (int i = 0; i < 16; ++i) {
      int t = grp * 16 + i;
      size_t rb = (size_t)(c * CH + t) * 4096;
      float xq = (float)pb0[rb + kk] + (float)pb1[rb + kk] + bqv;
      float xk = (float)pb0[rb + 1024 + kk] + (float)pb1[rb + 1024 + kk] + bkv;
      float xg = (float)pb0[rb + 2048 + kk] + (float)pb1[rb + 2048 + kk] + bgv;
      qv[i] = xq;
      kv[i] = 1.f / (1.f + expf(-xk));
      lraw[i] = fminf(xg, 0.f) - log1pf(expf(-fabsf(xg)));
      run += lraw[i];
    }
    gtot[grp][colL] = run;
    __syncthreads();
    float off = 0.f, lc = 0.f;
#pragma unroll
    for (int g2 = 0; g2 < 4; ++g2) {
      float v = gtot[g2][colL];
      if (g2 < grp) off += v;
      lc += v;
    }
    if (grp == 0) laC[(size_t)c * KD + kk] = lc;
    float run2 = off;
#pragma unroll
    for (int i = 0; i < 16; ++i) {
      int t = grp * 16 + i;
      run2 += lraw[i];
      size_t idx = (size_t)(c * CH + t) * KD + kk;
      qt[idx] = tobf(qv[i] * expf(run2));
      kt[idx] = tobf(kv[i] * expf(-run2));
      tr[colL][t] = tobf(kv[i] * expf(lc - run2));  // kbar, staged for transpose
    }
    __syncthreads();
#pragma unroll
    for (int i = 0; i < 16; ++i) {
      int row = grp + 4 * i;
      kbarT[((size_t)c * KD + kk0 + row) * 64 + colL] = tr[row][colL];
    }
  } else {
    const int vv0 = tile * 64;
    const float bvv = bv[vv0 + colL];
#pragma unroll
    for (int i = 0; i < 16; ++i) {
      int t = grp + 4 * i;
      size_t rb = (size_t)(c * CH + t) * 4096;
      float xv = (float)pb0[rb + 3072 + vv0 + colL]
               + (float)pb1[rb + 3072 + vv0 + colL] + bvv;
      tr[colL][t] = tobf(xv);
    }
    __syncthreads();
#pragma unroll
    for (int i = 0; i < 16; ++i) {
      int row = grp + 4 * i;
      vT[((size_t)c * VD + vv0 + row) * 64 + colL] = tr[row][colL];
    }
  }
}

// K-split QK^T partials body: Ppart[c][ks] = q~ slice @ k~ slice^T (fp32)
DEVI void qkt_body(const bf16* __restrict__ qt, const bf16* __restrict__ kt,
                   float* __restrict__ Ppart, int ks, int c, int tid)
{
  __shared__ __align__(16) bf16 sAq[3 * 64 * 32];
  __shared__ __align__(16) bf16 sBq[3 * 64 * 32];
  const int lane = tid & 63;
  const int wr = (tid >> 6) >> 1, wc = (tid >> 6) & 1;
  f32x4 acc[4];
#pragma unroll
  for (int i = 0; i < 4; ++i) acc[i] = fzero();
  gemm_core<64, 64>(qt + (size_t)c * CH * KD + ks * 256, KD, 0,
                    kt + (size_t)c * CH * KD + ks * 256, KD, 0, 256,
                    acc, sAq, sBq, tid);
  float* dst = Ppart + ((size_t)c * 4 + ks) * 4096;
#pragma unroll
  for (int m = 0; m < 2; ++m)
#pragma unroll
    for (int n = 0; n < 2; ++n) {
      f32x4 v = acc[m * 2 + n];
      int j = wc * 32 + n * 16 + (lane & 15);
#pragma unroll
      for (int r = 0; r < 4; ++r) {
        int t = wr * 32 + m * 16 + (lane >> 4) * 4 + r;
        dst[t * 64 + j] = v[r];
      }
    }
}

// fused U-GEMM + decay scan body (S in MFMA accumulator, fp32 across chunks).
DEVI void uscan_body(const bf16* __restrict__ vT, const bf16* __restrict__ kbarT,
                     const float* __restrict__ laC, bf16* __restrict__ Sstore,
                     float* __restrict__ Sinit, bf16* __restrict__ ScarryB,
                     float* __restrict__ dstate, int g, int bx, int by, int tid)
{
  __shared__ __align__(16) bf16 sAu[3 * 4096];  // [buf][ks*2048 + row*32 + kof]
  __shared__ __align__(16) bf16 sBu[3 * 4096];
  const int vv0 = bx * 64, kk0 = by * 64;
  const int lane = tid & 63;
  const int wr = (tid >> 6) >> 1, wc = (tid >> 6) & 1;
  const int srow = tid >> 2, skof = (tid & 3) * 8;

  auto stage = [&](int cl, int buf) {
    const int c = g * CPG + cl;
    const bf16* vP = vT + ((size_t)c * VD + vv0 + srow) * 64 + skof;
    const bf16* kP = kbarT + ((size_t)c * KD + kk0 + srow) * 64 + skof;
    gld16(vP,      sAu + buf * 4096 + tid * 8);
    gld16(vP + 32, sAu + buf * 4096 + 2048 + tid * 8);
    gld16(kP,      sBu + buf * 4096 + tid * 8);
    gld16(kP + 32, sBu + buf * 4096 + 2048 + tid * 8);
  };

  const int col0 = kk0 + wc * 32 + (lane & 15);
  const int row0 = vv0 + wr * 32 + (lane >> 4) * 4;

  f32x4 S[4];
  if (g == 0) {
#pragma unroll
    for (int i = 0; i < 4; ++i) S[i] = fzero();
  } else {
#pragma unroll
    for (int m = 0; m < 2; ++m)
#pragma unroll
      for (int n = 0; n < 2; ++n)
#pragma unroll
        for (int r = 0; r < 4; ++r)
          S[m * 2 + n][r] =
              Sinit[(size_t)(row0 + m * 16 + r) * KD + col0 + n * 16];
  }

  stage(0, 0);
  stage(1, 1);
  float ln0 = laC[(size_t)(g * CPG) * KD + col0];
  float ln1 = laC[(size_t)(g * CPG) * KD + col0 + 16];

  for (int cl = 0; cl < CPG; ++cl) {
    if (cl < CPG - 1) waitvm<4>();
    else              waitvm<0>();
    __builtin_amdgcn_s_barrier();
    __builtin_amdgcn_sched_barrier(0);
    const float d0 = expf(ln0), d1 = expf(ln1);
#pragma unroll
    for (int m = 0; m < 2; ++m)
#pragma unroll
      for (int r = 0; r < 4; ++r) {
        S[m * 2 + 0][r] *= d0;
        S[m * 2 + 1][r] *= d1;
      }
    int buf = cl % 3;
    const bf16* pA = sAu + buf * 4096;
    const bf16* pB = sBu + buf * 4096;
#pragma unroll
    for (int ks = 0; ks < 2; ++ks) {
      bf16x8 af[2], bfr[2];
#pragma unroll
      for (int m = 0; m < 2; ++m)
        af[m] = *(const bf16x8*)(pA + ks * 2048
                 + (wr * 32 + m * 16 + (lane & 15)) * 32 + (lane >> 4) * 8);
#pragma unroll
      for (int n = 0; n < 2; ++n)
        bfr[n] = *(const bf16x8*)(pB + ks * 2048
                 + (wc * 32 + n * 16 + (lane & 15)) * 32 + (lane >> 4) * 8);
#pragma unroll
      for (int m = 0; m < 2; ++m)
#pragma unroll
        for (int n = 0; n < 2; ++n)
          S[m * 2 + n] = __builtin_amdgcn_mfma_f32_16x16x32_bf16(
              af[m], bfr[n], S[m * 2 + n], 0, 0, 0);
    }
    // write S_c (bf16); stores precede next stage() so waitvm<4> counts only
    // the 4 prefetch loads.
    bf16* dst = Sstore + (size_t)cl * KD * VD;
#pragma unroll
    for (int m = 0; m < 2; ++m)
#pragma unroll
      for (int n = 0; n < 2; ++n)
#pragma unroll
        for (int r = 0; r < 4; ++r)
          dst[(size_t)(row0 + m * 16 + r) * KD + col0 + n * 16] =
              tobf(S[m * 2 + n][r]);
    if (cl + 1 < CPG) {
      ln0 = laC[(size_t)(g * CPG + cl + 1) * KD + col0];
      ln1 = laC[(size_t)(g * CPG + cl + 1) * KD + col0 + 16];
    }
    if (cl + 2 < CPG) stage(cl + 2, (cl + 2) % 3);
  }

  if (g < NGROUP - 1) {
#pragma unroll
    for (int m = 0; m < 2; ++m)
#pragma unroll
      for (int n = 0; n < 2; ++n)
#pragma unroll
        for (int r = 0; r < 4; ++r) {
          size_t o = (size_t)(row0 + m * 16 + r) * KD + col0 + n * 16;
          Sinit[o] = S[m * 2 + n][r];
          ScarryB[o] = tobf(S[m * 2 + n][r]);
        }
  } else {
    // final state -> dstate [kk][vv] via LDS transpose (reuse sAu as fp32)
    float* flds = (float*)sAu;               // 64x65 fp32 = 16.6KB < 24KB
    __syncthreads();
#pragma unroll
    for (int m = 0; m < 2; ++m)
#pragma unroll
      for (int n = 0; n < 2; ++n)
#pragma unroll
        for (int r = 0; r < 4; ++r)
          flds[(wr * 32 + m * 16 + (lane >> 4) * 4 + r) * 65
               + wc * 32 + n * 16 + (lane & 15)] = S[m * 2 + n][r];
    __syncthreads();
    const int kkL = tid & 63;
    const int vb0 = (tid >> 6) * 16;
    float* dp = dstate + (size_t)(kk0 + kkL) * VD + vv0 + vb0;
#pragma unroll
    for (int q = 0; q < 4; ++q) {
      float4 o = {flds[(vb0 + q * 4 + 0) * 65 + kkL],
                  flds[(vb0 + q * 4 + 1) * 65 + kkL],
                  flds[(vb0 + q * 4 + 2) * 65 + kkL],
                  flds[(vb0 + q * 4 + 3) * 65 + kkL]};
      *(float4*)(dp + q * 4) = o;
    }
  }
}

// union kernel: z=0 -> qkt (256 blocks), z=1 -> uscan g=0 (256 blocks).
__global__ __launch_bounds__(256) void k_qkt_uscan(
    const bf16* __restrict__ qt, const bf16* __restrict__ kt,
    float* __restrict__ Ppart,
    const bf16* __restrict__ vT, const bf16* __restrict__ kbarT,
    const float* __restrict__ laC, bf16* __restrict__ Sstore,
    float* __restrict__ Sinit, bf16* __restrict__ ScarryB,
    float* __restrict__ dstate)
{
  const int tid = threadIdx.x;
  if (blockIdx.z == 0) {
    const int flat = blockIdx.x + 16 * blockIdx.y;   // 0..255
    qkt_body(qt, kt, Ppart, flat & 3, flat >> 2, tid);
  } else {
    uscan_body(vT, kbarT, laC, Sstore, Sinit, ScarryB, dstate, 0,
               blockIdx.x, blockIdx.y, tid);
  }
}

// standalone uscan for g=1
__global__ __launch_bounds__(256) void k_uscan(
    const bf16* __restrict__ vT, const bf16* __restrict__ kbarT,
    const float* __restrict__ laC, bf16* __restrict__ Sstore,
    float* __restrict__ Sinit, bf16* __restrict__ ScarryB,
    float* __restrict__ dstate, int g)
{
  uscan_body(vT, kbarT, laC, Sstore, Sinit, ScarryB, dstate, g,
             blockIdx.x, blockIdx.y, threadIdx.x);
}

// fused: P assemble + inter GEMM (q~_c @ S_{c-1}) + PV (128-col slice)
// -> ob = bf16(intra + inter). grid (8 ntiles, CPG chunks).
__global__ __launch_bounds__(256) void k_inter2(
    const bf16* __restrict__ qt, const float* __restrict__ Ppart,
    const bf16* __restrict__ vT, const bf16* __restrict__ Sstore,
    const bf16* __restrict__ ScarryB, bf16* __restrict__ ob, int g)
{
  __shared__ __align__(16) bf16 sA[3 * 64 * 32];
  __shared__ __align__(16) bf16 sB[3 * 128 * 32];
  __shared__ __align__(16) bf16 Pl[64 * 72];
  __shared__ __align__(16) bf16 sV[128 * 72];
  const int cl = blockIdx.y, c = g * CPG + cl;
  const int n0 = blockIdx.x * 128;
  const int tid = threadIdx.x, lane = tid & 63;
  const int wr = (tid >> 6) >> 1, wc = (tid >> 6) & 1;

  // assemble P = sum of 4 K-partials, causal mask, bf16 into Pl
  {
    const float* base = Ppart + (size_t)c * 4 * 4096;
    const int i0 = tid * 16;
    const int t = tid >> 2;
    const int j0 = (tid & 3) * 16;
#pragma unroll
    for (int e = 0; e < 16; e += 4) {
      float4 s0 = *(const float4*)(base + 0 * 4096 + i0 + e);
      float4 s1 = *(const float4*)(base + 1 * 4096 + i0 + e);
      float4 s2 = *(const float4*)(base + 2 * 4096 + i0 + e);
      float4 s3 = *(const float4*)(base + 3 * 4096 + i0 + e);
      float sx = s0.x + s1.x + s2.x + s3.x;
      float sy = s0.y + s1.y + s2.y + s3.y;
      float sz = s0.z + s1.z + s2.z + s3.z;
      float sw = s0.w + s1.w + s2.w + s3.w;
      int j = j0 + e;
      Pl[t * 72 + j + 0] = (j + 0 <= t) ? tobf(sx) : tobf(0.f);
      Pl[t * 72 + j + 1] = (j + 1 <= t) ? tobf(sy) : tobf(0.f);
      Pl[t * 72 + j + 2] = (j + 2 <= t) ? tobf(sz) : tobf(0.f);
      Pl[t * 72 + j + 3] = (j + 3 <= t) ? tobf(sw) : tobf(0.f);
    }
  }
  __syncthreads();

  f32x4 acc[8];
#pragma unroll
  for (int i = 0; i < 8; ++i) acc[i] = fzero();
  if (c > 0) {
    const bf16* B = (cl == 0) ? ScarryB : Sstore + (size_t)(cl - 1) * KD * VD;
    gemm_core<64, 128>(qt + (size_t)c * CH * KD, KD, 0, B, KD, n0, KD,
                       acc, sA, sB, tid);
  }

  // stage V^T slice rows [n0, n0+128) and add PV into acc
#pragma unroll
  for (int rr = 0; rr < 4; ++rr) {
    int row = rr * 32 + (tid >> 3);
    int j0 = (tid & 7) * 8;
    bf16x8 vv = *(const bf16x8*)(vT + ((size_t)c * VD + n0 + row) * 64 + j0);
    *(bf16x8*)(sV + row * 72 + j0) = vv;
  }
  __syncthreads();
#pragma unroll
  for (int ks = 0; ks < 64; ks += 32) {
    bf16x8 af[2], bfr[4];
#pragma unroll
    for (int m = 0; m < 2; ++m)
      af[m] = *(const bf16x8*)(Pl + (wr * 32 + m * 16 + (lane & 15)) * 72
                               + ks + (lane >> 4) * 8);
#pragma unroll
    for (int n = 0; n < 4; ++n)
      bfr[n] = *(const bf16x8*)(sV + (wc * 64 + n * 16 + (lane & 15)) * 72
                                + ks + (lane >> 4) * 8);
#pragma unroll
    for (int m = 0; m < 2; ++m)
#pragma unroll
      for (int n = 0; n < 4; ++n)
        acc[m * 4 + n] = __builtin_amdgcn_mfma_f32_16x16x32_bf16(
            af[m], bfr[n], acc[m * 4 + n], 0, 0, 0);
  }

#pragma unroll
  for (int m = 0; m < 2; ++m)
#pragma unroll
    for (int n = 0; n < 4; ++n) {
      f32x4 v = acc[m * 4 + n];
      int col = wc * 64 + n * 16 + (lane & 15);
#pragma unroll
      for (int r = 0; r < 4; ++r) {
        int row = wr * 32 + m * 16 + (lane >> 4) * 4 + r;
        ob[((size_t)c * CH + row) * VD + n0 + col] = tobf(v[r]);
      }
    }
}

// y = ob @ Wo^T + bo. BN=64: grid (32, 32) = 1024 blocks, 4/CU.
__global__ __launch_bounds__(256) void k_out(
    const bf16* __restrict__ ob, const bf16* __restrict__ Wob,
    const float* __restrict__ bo, float* __restrict__ out)
{
  __shared__ __align__(16) bf16 sA[3 * 128 * 32];
  __shared__ __align__(16) bf16 sB[3 * 64 * 32];
  const int m0 = blockIdx.x * 128, n0 = blockIdx.y * 64;
  const int tid = threadIdx.x, lane = tid & 63;
  const int wr = (tid >> 6) >> 1, wc = (tid >> 6) & 1;
  f32x4 acc[8];
#pragma unroll
  for (int i = 0; i < 8; ++i) acc[i] = fzero();
  gemm_core<128, 64>(ob, VD, m0, Wob, VD, n0, VD, acc, sA, sB, tid);
#pragma unroll
  for (int m = 0; m < 4; ++m)
#pragma unroll
    for (int n = 0; n < 2; ++n) {
      f32x4 v = acc[m * 2 + n];
      int col = n0 + wc * 32 + n * 16 + (lane & 15);
      float b = bo[col];
#pragma unroll
      for (int r = 0; r < 4; ++r) {
        int row = m0 + wr * 64 + m * 16 + (lane >> 4) * 4 + r;
        out[(size_t)row * OD + col] = v[r] + b;
      }
    }
}

// ---------------------------------------------------------------------------
extern "C" void kernel_launch(void* const* d_in, const int* in_sizes, int n_in,
                              void* d_out, int out_size, void* d_ws, size_t ws_size,
                              hipStream_t stream)
{
  const float* hs = (const float*)d_in[0];
  const float* Wq = (const float*)d_in[1];
  const float* bq = (const float*)d_in[2];
  const float* Wk = (const float*)d_in[3];
  const float* bk = (const float*)d_in[4];
  const float* Wv = (const float*)d_in[5];
  const float* bv = (const float*)d_in[6];
  const float* Wg = (const float*)d_in[7];
  const float* bg = (const float*)d_in[8];
  const float* Wo = (const float*)d_in[9];
  const float* bo = (const float*)d_in[10];
  float* out = (float*)d_out;
  float* dstate = out + (size_t)T_ * OD;

  char* p = (char*)d_ws;
  auto alloc = [&](size_t b) -> char* {
    char* r = p; p += (b + 255) & ~(size_t)255; return r;
  };
  bf16* hsb    = (bf16*)alloc((size_t)T_ * H_ * 2);
  bf16* Wqb    = (bf16*)alloc((size_t)KD * H_ * 2);
  bf16* Wkb    = (bf16*)alloc((size_t)KD * H_ * 2);
  bf16* Wgb    = (bf16*)alloc((size_t)KD * H_ * 2);
  bf16* Wvb    = (bf16*)alloc((size_t)VD * H_ * 2);
  bf16* Wob    = (bf16*)alloc((size_t)OD * VD * 2);
  bf16* qt     = (bf16*)alloc((size_t)T_ * KD * 2);
  bf16* kt     = (bf16*)alloc((size_t)T_ * KD * 2);
  bf16* kbarT  = (bf16*)alloc((size_t)T_ * KD * 2);
  bf16* vT     = (bf16*)alloc((size_t)T_ * VD * 2);
  bf16* ob     = (bf16*)alloc((size_t)T_ * VD * 2);
  float* Sinit = (float*)alloc((size_t)KD * VD * 4);
  bf16* ScarryB= (bf16*)alloc((size_t)KD * VD * 2);
  bf16* Sstore = (bf16*)alloc((size_t)CPG * KD * VD * 2);   // 64 MB
  float* laC   = (float*)alloc((size_t)NCHUNK * KD * 4);
  float* Ppart = (float*)alloc((size_t)NCHUNK * 4 * 4096 * 4);
  bf16* pbuf   = (bf16*)alloc((size_t)2 * T_ * 4096 * 2);   // 64 MB partials
  if ((size_t)(p - (char*)d_ws) > ws_size) return;

  k_cvt6<<<(int)((CVT_TOT / 4 + 255) / 256), 256, 0, stream>>>(
      hs, Wq, Wk, Wg, Wv, Wo, hsb, Wqb, Wkb, Wgb, Wvb, Wob);

  k_projA<<<dim3(T_ / 128, 32, 2), 256, 0, stream>>>(
      hsb, Wqb, Wkb, Wgb, Wvb, pbuf);

  // fused bias+activation+prefix+transforms (projB+transform)
  k_ptrans<<<dim3(16, NCHUNK, 2), 256, 0, stream>>>(
      pbuf, bq, bk, bg, bv, qt, kt, kbarT, vT, laC);

  // co-scheduled: qkt (z=0) + uscan g=0 (z=1)
  k_qkt_uscan<<<dim3(16, 16, 2), 256, 0, stream>>>(
      qt, kt, Ppart, vT, kbarT, laC, Sstore, Sinit, ScarryB, dstate);

  k_inter2<<<dim3(8, CPG), 256, 0, stream>>>(
      qt, Ppart, vT, Sstore, ScarryB, ob, 0);
  k_uscan<<<dim3(16, 16), 256, 0, stream>>>(
      vT, kbarT, laC, Sstore, Sinit, ScarryB, dstate, 1);
  k_inter2<<<dim3(8, CPG), 256, 0, stream>>>(
      qt, Ppart, vT, Sstore, ScarryB, ob, 1);

  k_out<<<dim3(T_ / 128, OD / 64), 256, 0, stream>>>(ob, Wob, bo, out);
}

// Round 14
// 270.926 us; speedup vs baseline: 1.1271x; 1.0136x over previous
//
#include <hip/hip_runtime.h>
#include <stdint.h>
#include <stddef.h>

// ---------------------------------------------------------------------------
// SimpleRNN (gated linear attention) — chunked parallel formulation.
//   q = hs@Wq^T+bq ; k = sig(hs@Wk^T+bk) ; g = sig(hs@Wg^T+bg) ; v = hs@Wv^T+bv
//   S_t = diag(g_t) S_{t-1} + k_t v_t^T ; out_t = q_t S_t ; y = out@Wo^T+bo
// Chunked (C=64): la = within-chunk cumsum(log g), q~ = q*exp(la),
//   k~ = k*exp(-la), kbar = k*exp(laC-la)
//   out = tril(q~ k~^T) V  +  q~ @ S_prev ; U_c = kbar^T V ;
//   S_c = exp(laC) (.) S_{c-1} + U_c
//
// R14 = R13 + deeper co-scheduling of the tail via union kernels with a
// SHARED (max-size, not summed) LDS buffer:
//   union1: qkt ∥ uscan g0            (48KB -> 3/CU)
//   union2: inter2 g0 ∥ uscan g1->pbuf (64.5KB -> 2/CU; S double-buffer
//           reuses pbuf, free after ptrans)
//   union3: k_out half0 ∥ inter2 g1   (64.5KB -> 2/CU)
//   k_out half1
// ---------------------------------------------------------------------------

#define DEVI __device__ __forceinline__

typedef __bf16 bf16;
typedef __bf16 bf16x8 __attribute__((ext_vector_type(8)));
typedef __bf16 bf16x4 __attribute__((ext_vector_type(4)));
typedef float  f32x4  __attribute__((ext_vector_type(4)));

static constexpr int T_  = 4096;
static constexpr int H_  = 2048;
static constexpr int KD  = 1024;
static constexpr int VD  = 1024;
static constexpr int OD  = 2048;
static constexpr int CH  = 64;                 // chunk length
static constexpr int NCHUNK = T_ / CH;         // 64
static constexpr int NGROUP = 2;               // chunk groups
static constexpr int CPG    = NCHUNK / NGROUP; // 32

DEVI bf16 tobf(float f) {
  union { float f; uint32_t u; } x; x.f = f;
  uint32_t r = (x.u + 0x7FFFu + ((x.u >> 16) & 1u)) >> 16;  // RNE
  union { uint16_t s; bf16 b; } y; y.s = (uint16_t)r;
  return y.b;
}

DEVI f32x4 fzero() { f32x4 z = {0.f, 0.f, 0.f, 0.f}; return z; }

// async global->LDS, 16B per lane (lane-linear LDS destination).
DEVI void gld16(const bf16* g, bf16* l) {
  auto* g1 = reinterpret_cast<__attribute__((address_space(1))) uint32_t*>(
      (uintptr_t)g);
  auto* l3 = reinterpret_cast<__attribute__((address_space(3))) uint32_t*>(
      (uintptr_t)l);
  __builtin_amdgcn_global_load_lds(g1, l3, 16, 0, 0);
}

template<int N> DEVI void waitvm() {
  if constexpr (N == 0) asm volatile("s_waitcnt vmcnt(0)" ::: "memory");
  else if constexpr (N == 2) asm volatile("s_waitcnt vmcnt(2)" ::: "memory");
  else if constexpr (N == 3) asm volatile("s_waitcnt vmcnt(3)" ::: "memory");
  else if constexpr (N == 4) asm volatile("s_waitcnt vmcnt(4)" ::: "memory");
  else static_assert(N == 0, "unsupported vmcnt");
}

// C[m0..+BM, n0..+BN] += A[M,K] * B[N,K]^T, both row-major K-contiguous.
// 4 waves in 2x2; BK=32; 3-buffer counted pipeline (best measured).
template<int BM, int BN>
DEVI void gemm_core(const bf16* A, int lda, int m0,
                    const bf16* B, int ldb, int n0,
                    int K, f32x4* acc, bf16* sA, bf16* sB, int tid)
{
  constexpr int MR = BM / 32;
  constexpr int NR = BN / 32;
  constexpr int ASZ = BM * 32;
  constexpr int BSZ = BN * 32;
  constexpr int LOADS = BM / 64 + BN / 64;
  const int lane = tid & 63;
  const int wr = (tid >> 6) >> 1;
  const int wc = (tid >> 6) & 1;
  const int srow = tid >> 2;
  const int skof = (tid & 3) * 8;
  const bf16* aB = A + (size_t)(m0 + srow) * lda + skof;
  const bf16* bB = B + (size_t)(n0 + srow) * ldb + skof;

  auto stage = [&](int t, int buf) {
    const int k0 = t * 32;
#pragma unroll
    for (int r = 0; r < BM / 64; ++r)
      gld16(aB + (size_t)r * 64 * lda + k0, sA + buf * ASZ + r * 2048 + tid * 8);
#pragma unroll
    for (int r = 0; r < BN / 64; ++r)
      gld16(bB + (size_t)r * 64 * ldb + k0, sB + buf * BSZ + r * 2048 + tid * 8);
  };

  const int nt = K / 32;
  stage(0, 0);
  if (nt > 1) stage(1, 1);
  int cur = 0;
  for (int t = 0; t < nt; ++t) {
    if (t < nt - 1) waitvm<LOADS>();
    else            waitvm<0>();
    __builtin_amdgcn_s_barrier();
    __builtin_amdgcn_sched_barrier(0);
    if (t + 2 < nt) {
      int b2 = cur + 2; if (b2 >= 3) b2 -= 3;
      stage(t + 2, b2);
    }
    const bf16* pA = sA + cur * ASZ;
    const bf16* pB = sB + cur * BSZ;
    bf16x8 af[MR], bfr[NR];
#pragma unroll
    for (int m = 0; m < MR; ++m)
      af[m] = *(const bf16x8*)(pA + (wr * (MR * 16) + m * 16 + (lane & 15)) * 32
                               + (lane >> 4) * 8);
#pragma unroll
    for (int n = 0; n < NR; ++n)
      bfr[n] = *(const bf16x8*)(pB + (wc * (NR * 16) + n * 16 + (lane & 15)) * 32
                                + (lane >> 4) * 8);
#pragma unroll
    for (int m = 0; m < MR; ++m)
#pragma unroll
      for (int n = 0; n < NR; ++n)
        acc[m * NR + n] = __builtin_amdgcn_mfma_f32_16x16x32_bf16(
            af[m], bfr[n], acc[m * NR + n], 0, 0, 0);
    ++cur; if (cur >= 3) cur -= 3;
  }
}

// ---------------------------------------------------------------------------
static constexpr size_t CVT_HS = (size_t)T_ * H_;
static constexpr size_t CVT_W  = (size_t)KD * H_;
static constexpr size_t CVT_WO = (size_t)OD * VD;
static constexpr size_t CVT_TOT = CVT_HS + 4 * CVT_W + CVT_WO;

__global__ __launch_bounds__(256) void k_cvt6(
    const float* __restrict__ hs, const float* __restrict__ Wq,
    const float* __restrict__ Wk, const float* __restrict__ Wg,
    const float* __restrict__ Wv, const float* __restrict__ Wo,
    bf16* __restrict__ hsb, bf16* __restrict__ Wqb,
    bf16* __restrict__ Wkb, bf16* __restrict__ Wgb,
    bf16* __restrict__ Wvb, bf16* __restrict__ Wob)
{
  size_t i = ((size_t)blockIdx.x * 256 + threadIdx.x) * 4;
  if (i >= CVT_TOT) return;
  const float* s; bf16* d; size_t off;
  if (i < CVT_HS)                { s = hs; d = hsb; off = i; }
  else if (i < CVT_HS + CVT_W)   { s = Wq; d = Wqb; off = i - CVT_HS; }
  else if (i < CVT_HS + 2*CVT_W) { s = Wk; d = Wkb; off = i - CVT_HS - CVT_W; }
  else if (i < CVT_HS + 3*CVT_W) { s = Wg; d = Wgb; off = i - CVT_HS - 2*CVT_W; }
  else if (i < CVT_HS + 4*CVT_W) { s = Wv; d = Wvb; off = i - CVT_HS - 3*CVT_W; }
  else                           { s = Wo; d = Wob; off = i - CVT_HS - 4*CVT_W; }
  float4 v = *(const float4*)(s + off);
  bf16x4 o; o[0] = tobf(v.x); o[1] = tobf(v.y); o[2] = tobf(v.z); o[3] = tobf(v.w);
  *(bf16x4*)(d + off) = o;
}

// K-split projection GEMM: grid (32 m, 32 nseg, 2 kh); bf16 partials.
__global__ __launch_bounds__(256) void k_projA(
    const bf16* __restrict__ hsb,
    const bf16* __restrict__ Wqb, const bf16* __restrict__ Wkb,
    const bf16* __restrict__ Wgb, const bf16* __restrict__ Wvb,
    bf16* __restrict__ pbuf)
{
  __shared__ __align__(16) bf16 sA[3 * 128 * 32];
  __shared__ __align__(16) bf16 sB[3 * 128 * 32];
  const int m0 = blockIdx.x * 128;
  const int nseg = blockIdx.y;
  const int kh = blockIdx.z;
  const int seg = nseg >> 3;
  const int n0 = (nseg & 7) * 128;
  const bf16* W = seg == 0 ? Wqb : seg == 1 ? Wkb : seg == 2 ? Wgb : Wvb;
  const int tid = threadIdx.x, lane = tid & 63;
  const int wr = (tid >> 6) >> 1, wc = (tid >> 6) & 1;
  f32x4 acc[16];
#pragma unroll
  for (int i = 0; i < 16; ++i) acc[i] = fzero();
  gemm_core<128, 128>(hsb + kh * 1024, H_, m0, W + kh * 1024, H_, n0, 1024,
                      acc, sA, sB, tid);
  bf16* dst = pbuf + (size_t)kh * T_ * 4096;
#pragma unroll
  for (int m = 0; m < 4; ++m)
#pragma unroll
    for (int n = 0; n < 4; ++n) {
      f32x4 v = acc[m * 4 + n];
      int colF = seg * 1024 + n0 + wc * 64 + n * 16 + (lane & 15);
#pragma unroll
      for (int r = 0; r < 4; ++r) {
        int row = m0 + wr * 64 + m * 16 + (lane >> 4) * 4 + r;
        dst[(size_t)row * 4096 + colF] = tobf(v[r]);
      }
    }
}

// fused projB + transform: read K-half partials, bias+activations, chunk
// prefix, emit qt/kt/kbarT/vT/laC.
__global__ __launch_bounds__(256) void k_ptrans(
    const bf16* __restrict__ pbuf,
    const float* __restrict__ bq, const float* __restrict__ bk,
    const float* __restrict__ bg, const float* __restrict__ bv,
    bf16* __restrict__ qt, bf16* __restrict__ kt,
    bf16* __restrict__ kbarT, bf16* __restrict__ vT,
    float* __restrict__ laC)
{
  __shared__ bf16 tr[64][72];
  __shared__ float gtot[4][64];
  const int c = blockIdx.y, tile = blockIdx.x, path = blockIdx.z;
  const int tid = threadIdx.x;
  const int colL = tid & 63;
  const int grp = tid >> 6;
  const bf16* pb0 = pbuf;
  const bf16* pb1 = pbuf + (size_t)T_ * 4096;
  if (path == 0) {
    const int kk0 = tile * 64;
    const int kk = kk0 + colL;
    const float bqv = bq[kk], bkv = bk[kk], bgv = bg[kk];
    float qv[16], kv[16], lraw[16];
    float run = 0.f;
#pragma unroll
    for (int i = 0; i < 16; ++i) {
      int t = grp * 16 + i;
      size_t rb = (size_t)(c * CH + t) * 4096;
      float xq = (float)pb0[rb + kk] + (float)pb1[rb + kk] + bqv;
      float xk = (float)pb0[rb + 1024 + kk] + (float)pb1[rb + 1024 + kk] + bkv;
      float xg = (float)pb0[rb + 2048 + kk] + (float)pb1[rb + 2048 + kk] + bgv;
      qv[i] = xq;
      kv[i] = 1.f / (1.f + expf(-xk));
      lraw[i] = fminf(xg, 0.f) - log1pf(expf(-fabsf(xg)));
      run += lraw[i];
    }
    gtot[grp][colL] = run;
    __syncthreads();
    float off = 0.f, lc = 0.f;
#pragma unroll
    for (int g2 = 0; g2 < 4; ++g2) {
      float v = gtot[g2][colL];
      if (g2 < grp) off += v;
      lc += v;
    }
    if (grp == 0) laC[(size_t)c * KD + kk] = lc;
    float run2 = off;
#pragma unroll
    for (int i = 0; i < 16; ++i) {
      int t = grp * 16 + i;
      run2 += lraw[i];
      size_t idx = (size_t)(c * CH + t) * KD + kk;
      qt[idx] = tobf(qv[i] * expf(run2));
      kt[idx] = tobf(kv[i] * expf(-run2));
      tr[colL][t] = tobf(kv[i] * expf(lc - run2));
    }
    __syncthreads();
#pragma unroll
    for (int i = 0; i < 16; ++i) {
      int row = grp + 4 * i;
      kbarT[((size_t)c * KD + kk0 + row) * 64 + colL] = tr[row][colL];
    }
  } else {
    const int vv0 = tile * 64;
    const float bvv = bv[vv0 + colL];
#pragma unroll
    for (int i = 0; i < 16; ++i) {
      int t = grp + 4 * i;
      size_t rb = (size_t)(c * CH + t) * 4096;
      float xv = (float)pb0[rb + 3072 + vv0 + colL]
               + (float)pb1[rb + 3072 + vv0 + colL] + bvv;
      tr[colL][t] = tobf(xv);
    }
    __syncthreads();
#pragma unroll
    for (int i = 0; i < 16; ++i) {
      int row = grp + 4 * i;
      vT[((size_t)c * VD + vv0 + row) * 64 + colL] = tr[row][colL];
    }
  }
}

// ---------------- bodies taking an external LDS pointer --------------------

// qkt: Ppart[c][ks] = q~ slice @ k~ slice^T (fp32). LDS: 24KB.
DEVI void qkt_body(bf16* lds, const bf16* __restrict__ qt,
                   const bf16* __restrict__ kt, float* __restrict__ Ppart,
                   int ks, int c, int tid)
{
  bf16* sA = lds;             // 3*2048
  bf16* sB = lds + 3 * 2048;  // 3*2048
  const int lane = tid & 63;
  const int wr = (tid >> 6) >> 1, wc = (tid >> 6) & 1;
  f32x4 acc[4];
#pragma unroll
  for (int i = 0; i < 4; ++i) acc[i] = fzero();
  gemm_core<64, 64>(qt + (size_t)c * CH * KD + ks * 256, KD, 0,
                    kt + (size_t)c * CH * KD + ks * 256, KD, 0, 256,
                    acc, sA, sB, tid);
  float* dst = Ppart + ((size_t)c * 4 + ks) * 4096;
#pragma unroll
  for (int m = 0; m < 2; ++m)
#pragma unroll
    for (int n = 0; n < 2; ++n) {
      f32x4 v = acc[m * 2 + n];
      int j = wc * 32 + n * 16 + (lane & 15);
#pragma unroll
      for (int r = 0; r < 4; ++r) {
        int t = wr * 32 + m * 16 + (lane >> 4) * 4 + r;
        dst[t * 64 + j] = v[r];
      }
    }
}

// fused U-GEMM + decay scan (S in MFMA accumulator). LDS: 48KB.
DEVI void uscan_body(bf16* lds,
                     const bf16* __restrict__ vT, const bf16* __restrict__ kbarT,
                     const float* __restrict__ laC, bf16* __restrict__ Sstore,
                     float* __restrict__ Sinit, bf16* __restrict__ ScarryB,
                     float* __restrict__ dstate, int g, int bx, int by, int tid)
{
  bf16* sAu = lds;             // 3*4096
  bf16* sBu = lds + 3 * 4096;  // 3*4096
  const int vv0 = bx * 64, kk0 = by * 64;
  const int lane = tid & 63;
  const int wr = (tid >> 6) >> 1, wc = (tid >> 6) & 1;
  const int srow = tid >> 2, skof = (tid & 3) * 8;

  auto stage = [&](int cl, int buf) {
    const int c = g * CPG + cl;
    const bf16* vP = vT + ((size_t)c * VD + vv0 + srow) * 64 + skof;
    const bf16* kP = kbarT + ((size_t)c * KD + kk0 + srow) * 64 + skof;
    gld16(vP,      sAu + buf * 4096 + tid * 8);
    gld16(vP + 32, sAu + buf * 4096 + 2048 + tid * 8);
    gld16(kP,      sBu + buf * 4096 + tid * 8);
    gld16(kP + 32, sBu + buf * 4096 + 2048 + tid * 8);
  };

  const int col0 = kk0 + wc * 32 + (lane & 15);
  const int row0 = vv0 + wr * 32 + (lane >> 4) * 4;

  f32x4 S[4];
  if (g == 0) {
#pragma unroll
    for (int i = 0; i < 4; ++i) S[i] = fzero();
  } else {
#pragma unroll
    for (int m = 0; m < 2; ++m)
#pragma unroll
      for (int n = 0; n < 2; ++n)
#pragma unroll
        for (int r = 0; r < 4; ++r)
          S[m * 2 + n][r] =
              Sinit[(size_t)(row0 + m * 16 + r) * KD + col0 + n * 16];
  }

  stage(0, 0);
  stage(1, 1);
  float ln0 = laC[(size_t)(g * CPG) * KD + col0];
  float ln1 = laC[(size_t)(g * CPG) * KD + col0 + 16];

  for (int cl = 0; cl < CPG; ++cl) {
    if (cl < CPG - 1) waitvm<4>();
    else              waitvm<0>();
    __builtin_amdgcn_s_barrier();
    __builtin_amdgcn_sched_barrier(0);
    const float d0 = expf(ln0), d1 = expf(ln1);
#pragma unroll
    for (int m = 0; m < 2; ++m)
#pragma unroll
      for (int r = 0; r < 4; ++r) {
        S[m * 2 + 0][r] *= d0;
        S[m * 2 + 1][r] *= d1;
      }
    int buf = cl % 3;
    const bf16* pA = sAu + buf * 4096;
    const bf16* pB = sBu + buf * 4096;
#pragma unroll
    for (int ks = 0; ks < 2; ++ks) {
      bf16x8 af[2], bfr[2];
#pragma unroll
      for (int m = 0; m < 2; ++m)
        af[m] = *(const bf16x8*)(pA + ks * 2048
                 + (wr * 32 + m * 16 + (lane & 15)) * 32 + (lane >> 4) * 8);
#pragma unroll
      for (int n = 0; n < 2; ++n)
        bfr[n] = *(const bf16x8*)(pB + ks * 2048
                 + (wc * 32 + n * 16 + (lane & 15)) * 32 + (lane >> 4) * 8);
#pragma unroll
      for (int m = 0; m < 2; ++m)
#pragma unroll
        for (int n = 0; n < 2; ++n)
          S[m * 2 + n] = __builtin_amdgcn_mfma_f32_16x16x32_bf16(
              af[m], bfr[n], S[m * 2 + n], 0, 0, 0);
    }
    bf16* dst = Sstore + (size_t)cl * KD * VD;
#pragma unroll
    for (int m = 0; m < 2; ++m)
#pragma unroll
      for (int n = 0; n < 2; ++n)
#pragma unroll
        for (int r = 0; r < 4; ++r)
          dst[(size_t)(row0 + m * 16 + r) * KD + col0 + n * 16] =
              tobf(S[m * 2 + n][r]);
    if (cl + 1 < CPG) {
      ln0 = laC[(size_t)(g * CPG + cl + 1) * KD + col0];
      ln1 = laC[(size_t)(g * CPG + cl + 1) * KD + col0 + 16];
    }
    if (cl + 2 < CPG) stage(cl + 2, (cl + 2) % 3);
  }

  if (g < NGROUP - 1) {
#pragma unroll
    for (int m = 0; m < 2; ++m)
#pragma unroll
      for (int n = 0; n < 2; ++n)
#pragma unroll
        for (int r = 0; r < 4; ++r) {
          size_t o = (size_t)(row0 + m * 16 + r) * KD + col0 + n * 16;
          Sinit[o] = S[m * 2 + n][r];
          ScarryB[o] = tobf(S[m * 2 + n][r]);
        }
  } else {
    // final state -> dstate [kk][vv] via LDS transpose (reuse sAu as fp32)
    float* flds = (float*)sAu;               // 64x65 fp32 = 16.6KB < 24KB
    __syncthreads();
#pragma unroll
    for (int m = 0; m < 2; ++m)
#pragma unroll
      for (int n = 0; n < 2; ++n)
#pragma unroll
        for (int r = 0; r < 4; ++r)
          flds[(wr * 32 + m * 16 + (lane >> 4) * 4 + r) * 65
               + wc * 32 + n * 16 + (lane & 15)] = S[m * 2 + n][r];
    __syncthreads();
    const int kkL = tid & 63;
    const int vb0 = (tid >> 6) * 16;
    float* dp = dstate + (size_t)(kk0 + kkL) * VD + vv0 + vb0;
#pragma unroll
    for (int q = 0; q < 4; ++q) {
      float4 o = {flds[(vb0 + q * 4 + 0) * 65 + kkL],
                  flds[(vb0 + q * 4 + 1) * 65 + kkL],
                  flds[(vb0 + q * 4 + 2) * 65 + kkL],
                  flds[(vb0 + q * 4 + 3) * 65 + kkL]};
      *(float4*)(dp + q * 4) = o;
    }
  }
}

// inter2: P assemble + inter GEMM + PV -> ob. LDS: 64.5KB.
DEVI void inter2_body(bf16* lds,
                      const bf16* __restrict__ qt, const float* __restrict__ Ppart,
                      const bf16* __restrict__ vT, const bf16* __restrict__ Sbase,
                      const bf16* __restrict__ ScarryB, bf16* __restrict__ ob,
                      int g, int n0, int cl, int tid)
{
  bf16* sA = lds;              // 3*64*32  = 6144
  bf16* sB = lds + 6144;       // 3*128*32 = 12288
  bf16* Pl = lds + 18432;      // 64*72    = 4608
  bf16* sV = lds + 23040;      // 128*72   = 9216   (total 32256)
  const int c = g * CPG + cl;
  const int lane = tid & 63;
  const int wr = (tid >> 6) >> 1, wc = (tid >> 6) & 1;

  {
    const float* base = Ppart + (size_t)c * 4 * 4096;
    const int i0 = tid * 16;
    const int t = tid >> 2;
    const int j0 = (tid & 3) * 16;
#pragma unroll
    for (int e = 0; e < 16; e += 4) {
      float4 s0 = *(const float4*)(base + 0 * 4096 + i0 + e);
      float4 s1 = *(const float4*)(base + 1 * 4096 + i0 + e);
      float4 s2 = *(const float4*)(base + 2 * 4096 + i0 + e);
      float4 s3 = *(const float4*)(base + 3 * 4096 + i0 + e);
      float sx = s0.x + s1.x + s2.x + s3.x;
      float sy = s0.y + s1.y + s2.y + s3.y;
      float sz = s0.z + s1.z + s2.z + s3.z;
      float sw = s0.w + s1.w + s2.w + s3.w;
      int j = j0 + e;
      Pl[t * 72 + j + 0] = (j + 0 <= t) ? tobf(sx) : tobf(0.f);
      Pl[t * 72 + j + 1] = (j + 1 <= t) ? tobf(sy) : tobf(0.f);
      Pl[t * 72 + j + 2] = (j + 2 <= t) ? tobf(sz) : tobf(0.f);
      Pl[t * 72 + j + 3] = (j + 3 <= t) ? tobf(sw) : tobf(0.f);
    }
  }
  __syncthreads();

  f32x4 acc[8];
#pragma unroll
  for (int i = 0; i < 8; ++i) acc[i] = fzero();
  if (c > 0) {
    const bf16* B = (cl == 0) ? ScarryB : Sbase + (size_t)(cl - 1) * KD * VD;
    gemm_core<64, 128>(qt + (size_t)c * CH * KD, KD, 0, B, KD, n0, KD,
                       acc, sA, sB, tid);
  }

#pragma unroll
  for (int rr = 0; rr < 4; ++rr) {
    int row = rr * 32 + (tid >> 3);
    int j0 = (tid & 7) * 8;
    bf16x8 vv = *(const bf16x8*)(vT + ((size_t)c * VD + n0 + row) * 64 + j0);
    *(bf16x8*)(sV + row * 72 + j0) = vv;
  }
  __syncthreads();
#pragma unroll
  for (int ks = 0; ks < 64; ks += 32) {
    bf16x8 af[2], bfr[4];
#pragma unroll
    for (int m = 0; m < 2; ++m)
      af[m] = *(const bf16x8*)(Pl + (wr * 32 + m * 16 + (lane & 15)) * 72
                               + ks + (lane >> 4) * 8);
#pragma unroll
    for (int n = 0; n < 4; ++n)
      bfr[n] = *(const bf16x8*)(sV + (wc * 64 + n * 16 + (lane & 15)) * 72
                                + ks + (lane >> 4) * 8);
#pragma unroll
    for (int m = 0; m < 2; ++m)
#pragma unroll
      for (int n = 0; n < 4; ++n)
        acc[m * 4 + n] = __builtin_amdgcn_mfma_f32_16x16x32_bf16(
            af[m], bfr[n], acc[m * 4 + n], 0, 0, 0);
  }

#pragma unroll
  for (int m = 0; m < 2; ++m)
#pragma unroll
    for (int n = 0; n < 4; ++n) {
      f32x4 v = acc[m * 4 + n];
      int col = wc * 64 + n * 16 + (lane & 15);
#pragma unroll
      for (int r = 0; r < 4; ++r) {
        int row = wr * 32 + m * 16 + (lane >> 4) * 4 + r;
        ob[((size_t)c * CH + row) * VD + n0 + col] = tobf(v[r]);
      }
    }
}

// k_out tile body: out[m0..+128, n0..+64]. LDS: 36KB.
DEVI void kout_body(bf16* lds,
                    const bf16* __restrict__ ob, const bf16* __restrict__ Wob,
                    const float* __restrict__ bo, float* __restrict__ out,
                    int m0, int n0, int tid)
{
  bf16* sA = lds;              // 3*128*32 = 12288
  bf16* sB = lds + 12288;      // 3*64*32  = 6144
  const int lane = tid & 63;
  const int wr = (tid >> 6) >> 1, wc = (tid >> 6) & 1;
  f32x4 acc[8];
#pragma unroll
  for (int i = 0; i < 8; ++i) acc[i] = fzero();
  gemm_core<128, 64>(ob, VD, m0, Wob, VD, n0, VD, acc, sA, sB, tid);
#pragma unroll
  for (int m = 0; m < 4; ++m)
#pragma unroll
    for (int n = 0; n < 2; ++n) {
      f32x4 v = acc[m * 2 + n];
      int col = n0 + wc * 32 + n * 16 + (lane & 15);
      float b = bo[col];
#pragma unroll
      for (int r = 0; r < 4; ++r) {
        int row = m0 + wr * 64 + m * 16 + (lane >> 4) * 4 + r;
        out[(size_t)row * OD + col] = v[r] + b;
      }
    }
}

// ---------------- union kernels (shared max-size LDS) ----------------------

// union1: z=0 qkt (256 blocks), z=1 uscan g=0. LDS 48KB -> 3/CU.
__global__ __launch_bounds__(256) void k_union1(
    const bf16* __restrict__ qt, const bf16* __restrict__ kt,
    float* __restrict__ Ppart,
    const bf16* __restrict__ vT, const bf16* __restrict__ kbarT,
    const float* __restrict__ laC, bf16* __restrict__ Sstore,
    float* __restrict__ Sinit, bf16* __restrict__ ScarryB,
    float* __restrict__ dstate)
{
  __shared__ __align__(16) bf16 lds[6 * 4096];   // 48KB
  const int tid = threadIdx.x;
  if (blockIdx.z == 0) {
    const int flat = blockIdx.x + 16 * blockIdx.y;
    qkt_body(lds, qt, kt, Ppart, flat & 3, flat >> 2, tid);
  } else {
    uscan_body(lds, vT, kbarT, laC, Sstore, Sinit, ScarryB, dstate, 0,
               blockIdx.x, blockIdx.y, tid);
  }
}

// union2: z=0 inter2 g=0 -> ob (reads Sstore), z=1 uscan g=1 -> Sstore2.
// LDS 64.5KB -> 2/CU.
__global__ __launch_bounds__(256) void k_union2(
    const bf16* __restrict__ qt, const float* __restrict__ Ppart,
    const bf16* __restrict__ vT, const bf16* __restrict__ Sstore,
    const bf16* __restrict__ ScarryB, bf16* __restrict__ ob,
    const bf16* __restrict__ kbarT, const float* __restrict__ laC,
    bf16* __restrict__ Sstore2, float* __restrict__ Sinit,
    float* __restrict__ dstate)
{
  __shared__ __align__(16) bf16 lds[32256];      // 64.5KB
  const int tid = threadIdx.x;
  if (blockIdx.z == 0) {
    const int flat = blockIdx.x + 16 * blockIdx.y;   // 0..255
    inter2_body(lds, qt, Ppart, vT, Sstore, ScarryB, ob, 0,
                (flat & 7) * 128, flat >> 3, tid);
  } else {
    uscan_body(lds, vT, kbarT, laC, Sstore2, Sinit, (bf16*)nullptr, dstate, 1,
               blockIdx.x, blockIdx.y, tid);
  }
}

// union3: z<2 k_out half0 (rows 0..2047, 512 blocks), z=2 inter2 g=1
// (reads Sstore2 + ScarryB). LDS 64.5KB -> 2/CU.
__global__ __launch_bounds__(256) void k_union3(
    const bf16* __restrict__ ob, const bf16* __restrict__ Wob,
    const float* __restrict__ bo, float* __restrict__ out,
    const bf16* __restrict__ qt, const float* __restrict__ Ppart,
    const bf16* __restrict__ vT, const bf16* __restrict__ Sstore2,
    const bf16* __restrict__ ScarryB, bf16* __restrict__ obw)
{
  __shared__ __align__(16) bf16 lds[32256];      // 64.5KB
  const int tid = threadIdx.x;
  if (blockIdx.z < 2) {
    const int idx = blockIdx.z * 256 + blockIdx.x + 16 * blockIdx.y; // 0..511
    kout_body(lds, ob, Wob, bo, out, (idx & 15) * 128, (idx >> 4) * 64, tid);
  } else {
    const int flat = blockIdx.x + 16 * blockIdx.y;   // 0..255
    inter2_body(lds, qt, Ppart, vT, Sstore2, ScarryB, obw, 1,
                (flat & 7) * 128, flat >> 3, tid);
  }
}

// k_out half1: rows 2048..4095. grid (16, 32).
__global__ __launch_bounds__(256) void k_out_h1(
    const bf16* __restrict__ ob, const bf16* __restrict__ Wob,
    const float* __restrict__ bo, float* __restrict__ out)
{
  __shared__ __align__(16) bf16 lds[3 * 128 * 32 + 3 * 64 * 32];  // 36KB
  kout_body(lds, ob, Wob, bo, out, (blockIdx.x + 16) * 128,
            blockIdx.y * 64, threadIdx.x);
}

// ---------------------------------------------------------------------------
extern "C" void kernel_launch(void* const* d_in, const int* in_sizes, int n_in,
                              void* d_out, int out_size, void* d_ws, size_t ws_size,
                              hipStream_t stream)
{
  const float* hs = (const float*)d_in[0];
  const float* Wq = (const float*)d_in[1];
  const float* bq = (const float*)d_in[2];
  const float* Wk = (const float*)d_in[3];
  const float* bk = (const float*)d_in[4];
  const float* Wv = (const float*)d_in[5];
  const float* bv = (const float*)d_in[6];
  const float* Wg = (const float*)d_in[7];
  const float* bg = (const float*)d_in[8];
  const float* Wo = (const float*)d_in[9];
  const float* bo = (const float*)d_in[10];
  float* out = (float*)d_out;
  float* dstate = out + (size_t)T_ * OD;

  char* p = (char*)d_ws;
  auto alloc = [&](size_t b) -> char* {
    char* r = p; p += (b + 255) & ~(size_t)255; return r;
  };
  bf16* hsb    = (bf16*)alloc((size_t)T_ * H_ * 2);
  bf16* Wqb    = (bf16*)alloc((size_t)KD * H_ * 2);
  bf16* Wkb    = (bf16*)alloc((size_t)KD * H_ * 2);
  bf16* Wgb    = (bf16*)alloc((size_t)KD * H_ * 2);
  bf16* Wvb    = (bf16*)alloc((size_t)VD * H_ * 2);
  bf16* Wob    = (bf16*)alloc((size_t)OD * VD * 2);
  bf16* qt     = (bf16*)alloc((size_t)T_ * KD * 2);
  bf16* kt     = (bf16*)alloc((size_t)T_ * KD * 2);
  bf16* kbarT  = (bf16*)alloc((size_t)T_ * KD * 2);
  bf16* vT     = (bf16*)alloc((size_t)T_ * VD * 2);
  bf16* ob     = (bf16*)alloc((size_t)T_ * VD * 2);
  float* Sinit = (float*)alloc((size_t)KD * VD * 4);
  bf16* ScarryB= (bf16*)alloc((size_t)KD * VD * 2);
  bf16* Sstore = (bf16*)alloc((size_t)CPG * KD * VD * 2);   // 64 MB
  float* laC   = (float*)alloc((size_t)NCHUNK * KD * 4);
  float* Ppart = (float*)alloc((size_t)NCHUNK * 4 * 4096 * 4);
  bf16* pbuf   = (bf16*)alloc((size_t)2 * T_ * 4096 * 2);   // 64 MB partials
  if ((size_t)(p - (char*)d_ws) > ws_size) return;

  // Sstore2 (second S buffer for group 1) reuses pbuf (free after ptrans).
  bf16* Sstore2 = pbuf;

  k_cvt6<<<(int)((CVT_TOT / 4 + 255) / 256), 256, 0, stream>>>(
      hs, Wq, Wk, Wg, Wv, Wo, hsb, Wqb, Wkb, Wgb, Wvb, Wob);

  k_projA<<<dim3(T_ / 128, 32, 2), 256, 0, stream>>>(
      hsb, Wqb, Wkb, Wgb, Wvb, pbuf);

  k_ptrans<<<dim3(16, NCHUNK, 2), 256, 0, stream>>>(
      pbuf, bq, bk, bg, bv, qt, kt, kbarT, vT, laC);

  // qkt ∥ uscan g0
  k_union1<<<dim3(16, 16, 2), 256, 0, stream>>>(
      qt, kt, Ppart, vT, kbarT, laC, Sstore, Sinit, ScarryB, dstate);

  // inter2 g0 ∥ uscan g1 (writes Sstore2 = pbuf; pbuf consumed by ptrans)
  k_union2<<<dim3(16, 16, 2), 256, 0, stream>>>(
      qt, Ppart, vT, Sstore, ScarryB, ob, kbarT, laC, Sstore2, Sinit, dstate);

  // k_out half0 (rows 0..2047, from inter2 g0) ∥ inter2 g1 (reads Sstore2)
  k_union3<<<dim3(16, 16, 3), 256, 0, stream>>>(
      ob, Wob, bo, out, qt, Ppart, vT, Sstore2, ScarryB, ob);

  // k_out half1 (rows 2048..4095, from inter2 g1)
  k_out_h1<<<dim3(16, 32), 256, 0, stream>>>(ob, Wob, bo, out);
}